// Round 1
// baseline (1190.066 us; speedup 1.0000x reference)
//
#include <hip/hip_runtime.h>
#include <stdint.h>

#define B_ 8
#define S_ 2048
#define E_ 2048
#define H_ 16
#define DH_ 128
#define M_ 1024

typedef float f32x4 __attribute__((ext_vector_type(4)));
typedef __bf16 bf16x8 __attribute__((ext_vector_type(8)));
typedef unsigned short ushort8 __attribute__((ext_vector_type(8)));
typedef unsigned short ushort4v __attribute__((ext_vector_type(4)));
typedef float float4v __attribute__((ext_vector_type(4)));

static __device__ __forceinline__ unsigned short f2bf(float f) {
  unsigned int u = __builtin_bit_cast(unsigned int, f);
  u += 0x7fffu + ((u >> 16) & 1u);
  return (unsigned short)(u >> 16);
}

static __device__ __forceinline__ f32x4 mfma16(ushort8 a, ushort8 b, f32x4 c) {
  return __builtin_amdgcn_mfma_f32_16x16x32_bf16(
      __builtin_bit_cast(bf16x8, a), __builtin_bit_cast(bf16x8, b), c, 0, 0, 0);
}

static __device__ __forceinline__ void gload_lds16(const void* g, void* l) {
  __builtin_amdgcn_global_load_lds(
      (const __attribute__((address_space(1))) unsigned int*)g,
      (__attribute__((address_space(3))) unsigned int*)l, 16, 0, 0);
}

// ---------------- conversion kernels ----------------

__global__ void cvt_bf16(const float* __restrict__ in, unsigned short* __restrict__ out, int n4) {
  int i = blockIdx.x * blockDim.x + threadIdx.x;
  int stride = gridDim.x * blockDim.x;
  for (; i < n4; i += stride) {
    float4v v = ((const float4v*)in)[i];
    ushort4v o;
    o[0] = f2bf(v[0]); o[1] = f2bf(v[1]); o[2] = f2bf(v[2]); o[3] = f2bf(v[3]);
    ((ushort4v*)out)[i] = o;
  }
}

__global__ void addcvt_bf16(const float* __restrict__ a, const float* __restrict__ b,
                            unsigned short* __restrict__ out, int n4) {
  int i = blockIdx.x * blockDim.x + threadIdx.x;
  int stride = gridDim.x * blockDim.x;
  for (; i < n4; i += stride) {
    float4v va = ((const float4v*)a)[i];
    float4v vb = ((const float4v*)b)[i];
    ushort4v o;
    o[0] = f2bf(va[0] + vb[0]); o[1] = f2bf(va[1] + vb[1]);
    o[2] = f2bf(va[2] + vb[2]); o[3] = f2bf(va[3] + vb[3]);
    ((ushort4v*)out)[i] = o;
  }
}

// batched transpose + f32->bf16: in[z][R][C] -> out[z][C][R]
__global__ __launch_bounds__(256) void transpose_cvt(const float* __restrict__ in,
                                                     unsigned short* __restrict__ out,
                                                     int R, int C) {
  __shared__ float t[64][65];
  const int tx = threadIdx.x & 63, ty = threadIdx.x >> 6;  // ty in 0..3
  const size_t base = (size_t)blockIdx.z * R * C;
  const int r0 = blockIdx.y * 64, c0 = blockIdx.x * 64;
#pragma unroll
  for (int i = 0; i < 64; i += 4)
    t[i + ty][tx] = in[base + (size_t)(r0 + i + ty) * C + (c0 + tx)];
  __syncthreads();
#pragma unroll
  for (int i = 0; i < 64; i += 4)
    out[base + (size_t)(c0 + i + ty) * R + (r0 + tx)] = f2bf(t[tx][i + ty]);
}

// ---------------- GEMM: C = A(M x K) * BT(N x K)^T + bias ----------------
// EPI 0: write bf16 Q in (B,H,S,Dh) layout, bias = bq (flat H*Dh)
// EPI 1: write f32 out row-major (M x N), bias = bd (flat N)
template <int EPI>
__global__ __launch_bounds__(256) void gemm_bt(const unsigned short* __restrict__ A,
                                               const unsigned short* __restrict__ BT,
                                               const float* __restrict__ bias,
                                               void* __restrict__ Cout,
                                               int Mdim, int Ndim, int Kdim) {
  __shared__ __align__(16) unsigned short a_sm[128 * 64];
  __shared__ __align__(16) unsigned short b_sm[128 * 64];
  const int tid = threadIdx.x;
  const int w = tid >> 6, lane = tid & 63;
  const int l16 = lane & 15, l4 = lane >> 4;
  const int wr = w >> 1, wc = w & 1;
  const int m0 = blockIdx.y << 7, n0 = blockIdx.x << 7;

  f32x4 acc[4][4];
#pragma unroll
  for (int i = 0; i < 4; ++i)
#pragma unroll
    for (int j = 0; j < 4; ++j) acc[i][j] = (f32x4)(0.f);

  const int nkt = Kdim >> 6;
  for (int kt = 0; kt < nkt; ++kt) {
    const unsigned short* Ak = A + (size_t)m0 * Kdim + kt * 64;
    const unsigned short* Bk = BT + (size_t)n0 * Kdim + kt * 64;
#pragma unroll
    for (int i = 0; i < 4; ++i) {
      const int c = i * 4 + w;
      const int row = c * 8 + (lane >> 3);
      const int col = (lane & 7) * 8;
      gload_lds16(Ak + (size_t)row * Kdim + col, &a_sm[c * 512 + lane * 8]);
      gload_lds16(Bk + (size_t)row * Kdim + col, &b_sm[c * 512 + lane * 8]);
    }
    __syncthreads();
#pragma unroll
    for (int kk = 0; kk < 2; ++kk) {
      ushort8 af[4], bf[4];
#pragma unroll
      for (int f = 0; f < 4; ++f) {
        af[f] = *(const ushort8*)&a_sm[(wr * 64 + f * 16 + l16) * 64 + kk * 32 + l4 * 8];
        bf[f] = *(const ushort8*)&b_sm[(wc * 64 + f * 16 + l16) * 64 + kk * 32 + l4 * 8];
      }
#pragma unroll
      for (int fr = 0; fr < 4; ++fr)
#pragma unroll
        for (int fc = 0; fc < 4; ++fc)
          acc[fr][fc] = mfma16(af[fr], bf[fc], acc[fr][fc]);
    }
    __syncthreads();
  }

#pragma unroll
  for (int fr = 0; fr < 4; ++fr) {
    const int mb = m0 + wr * 64 + fr * 16 + l4 * 4;
#pragma unroll
    for (int fc = 0; fc < 4; ++fc) {
      const int n = n0 + wc * 64 + fc * 16 + l16;
      const float bv = bias[n];
#pragma unroll
      for (int r = 0; r < 4; ++r) {
        const float v = acc[fr][fc][r] + bv;
        const int m = mb + r;
        if (EPI == 0) {
          const int b = m >> 11, s = m & 2047, h = n >> 7, d = n & 127;
          ((unsigned short*)Cout)[(((size_t)(b * 16 + h) << 11) + s) * 128 + d] = f2bf(v);
        } else {
          ((float*)Cout)[(size_t)m * Ndim + n] = v;
        }
      }
    }
  }
}

// ---------------- fused attention ----------------
// grid: (S/128, B*H); block 256 (4 waves x 32 rows)
__global__ __launch_bounds__(256) void attn_kernel(const unsigned short* __restrict__ Qb,
                                                   const unsigned short* __restrict__ Kb,
                                                   const unsigned short* __restrict__ VT,
                                                   unsigned short* __restrict__ Ob) {
  const int bh = blockIdx.y, b = bh >> 4, h = bh & 15;
  const int s0 = blockIdx.x << 7;
  const int tid = threadIdx.x, w = tid >> 6, lane = tid & 63;
  const int l16 = lane & 15, l4 = lane >> 4;
  const int sw = s0 + w * 32;
  __shared__ __align__(16) unsigned short p_lds[4][32][72];  // padded: row stride 144B

  ushort8 aq[2][4];
  {
    const unsigned short* Qbase = Qb + ((size_t)(b * 16 + h) * S_ + sw) * DH_;
#pragma unroll
    for (int rb = 0; rb < 2; ++rb) {
      const unsigned short* qrow = Qbase + (size_t)(rb * 16 + l16) * DH_ + l4 * 8;
#pragma unroll
      for (int kk = 0; kk < 4; ++kk) aq[rb][kk] = *(const ushort8*)(qrow + kk * 32);
    }
  }

  float m_run[2][4], l_run[2][4];
  f32x4 o_acc[2][8];
#pragma unroll
  for (int rb = 0; rb < 2; ++rb) {
#pragma unroll
    for (int r = 0; r < 4; ++r) { m_run[rb][r] = -1e30f; l_run[rb][r] = 0.f; }
#pragma unroll
    for (int nc = 0; nc < 8; ++nc) o_acc[rb][nc] = (f32x4)(0.f);
  }

  const unsigned short* Kh = Kb + (size_t)h * M_ * DH_;
  const unsigned short* Vh = VT + (size_t)h * DH_ * M_;
  const float scale = 0.022097086912079608f;  // 1/sqrt(2048)

  for (int mc = 0; mc < 16; ++mc) {
    const int m0 = mc << 6;
    f32x4 sa[2][4];
#pragma unroll
    for (int rb = 0; rb < 2; ++rb)
#pragma unroll
      for (int nc = 0; nc < 4; ++nc) sa[rb][nc] = (f32x4)(0.f);

#pragma unroll
    for (int nc = 0; nc < 4; ++nc) {
      const unsigned short* krow = Kh + (size_t)(m0 + nc * 16 + l16) * DH_ + l4 * 8;
#pragma unroll
      for (int kk = 0; kk < 4; ++kk) {
        ushort8 bk = *(const ushort8*)(krow + kk * 32);
        sa[0][nc] = mfma16(aq[0][kk], bk, sa[0][nc]);
        sa[1][nc] = mfma16(aq[1][kk], bk, sa[1][nc]);
      }
    }

#pragma unroll
    for (int rb = 0; rb < 2; ++rb) {
#pragma unroll
      for (int r = 0; r < 4; ++r) {
        float v = fmaxf(fmaxf(sa[rb][0][r], sa[rb][1][r]), fmaxf(sa[rb][2][r], sa[rb][3][r]));
        v = fmaxf(v, __shfl_xor(v, 1, 64));
        v = fmaxf(v, __shfl_xor(v, 2, 64));
        v = fmaxf(v, __shfl_xor(v, 4, 64));
        v = fmaxf(v, __shfl_xor(v, 8, 64));
        const float pmax = v * scale;
        const float mold = m_run[rb][r];
        const float mnew = fmaxf(mold, pmax);
        const float alpha = __expf(mold - mnew);
        m_run[rb][r] = mnew;
#pragma unroll
        for (int nc = 0; nc < 8; ++nc) o_acc[rb][nc][r] *= alpha;
        float rsum = 0.f;
#pragma unroll
        for (int nc = 0; nc < 4; ++nc) {
          float p = __expf(sa[rb][nc][r] * scale - mnew);
          sa[rb][nc][r] = p;
          rsum += p;
        }
        rsum += __shfl_xor(rsum, 1, 64);
        rsum += __shfl_xor(rsum, 2, 64);
        rsum += __shfl_xor(rsum, 4, 64);
        rsum += __shfl_xor(rsum, 8, 64);
        l_run[rb][r] = l_run[rb][r] * alpha + rsum;
      }
#pragma unroll
      for (int nc = 0; nc < 4; ++nc)
#pragma unroll
        for (int r = 0; r < 4; ++r)
          p_lds[w][rb * 16 + l4 * 4 + r][nc * 16 + l16] = f2bf(sa[rb][nc][r]);
    }

#pragma unroll
    for (int rb = 0; rb < 2; ++rb) {
      ushort8 pf[2];
#pragma unroll
      for (int kk = 0; kk < 2; ++kk)
        pf[kk] = *(const ushort8*)&p_lds[w][rb * 16 + l16][kk * 32 + l4 * 8];
#pragma unroll
      for (int nc = 0; nc < 8; ++nc) {
        const unsigned short* vrow = Vh + (size_t)(nc * 16 + l16) * M_ + m0 + l4 * 8;
#pragma unroll
        for (int kk = 0; kk < 2; ++kk) {
          ushort8 bv = *(const ushort8*)(vrow + kk * 32);
          o_acc[rb][nc] = mfma16(pf[kk], bv, o_acc[rb][nc]);
        }
      }
    }
  }

#pragma unroll
  for (int rb = 0; rb < 2; ++rb)
#pragma unroll
    for (int r = 0; r < 4; ++r) {
      const float inv = 1.0f / l_run[rb][r];
      const int srow = sw + rb * 16 + l4 * 4 + r;
      unsigned short* orow = Ob + ((size_t)b * S_ + srow) * (H_ * DH_) + h * DH_;
#pragma unroll
      for (int nc = 0; nc < 8; ++nc)
        orow[nc * 16 + l16] = f2bf(o_acc[rb][nc][r] * inv);
    }
}

// ---------------- launcher ----------------

extern "C" void kernel_launch(void* const* d_in, const int* in_sizes, int n_in,
                              void* d_out, int out_size, void* d_ws, size_t ws_size,
                              hipStream_t stream) {
  const float* X   = (const float*)d_in[0];
  const float* Wq  = (const float*)d_in[1];
  const float* bq  = (const float*)d_in[2];
  const float* Kp  = (const float*)d_in[3];
  const float* Cal = (const float*)d_in[4];
  const float* V   = (const float*)d_in[5];
  const float* Wd  = (const float*)d_in[6];
  const float* bd  = (const float*)d_in[7];

  char* ws = (char*)d_ws;
  unsigned short* Xbf = (unsigned short*)(ws + 0);          // 67108864 B (reused as Ob)
  unsigned short* Ob  = Xbf;                                 // alias: X dead after GEMM1
  unsigned short* Qb  = (unsigned short*)(ws + 67108864);   // 67108864 B
  unsigned short* WqT = (unsigned short*)(ws + 134217728);  // 8388608 B
  unsigned short* WdT = (unsigned short*)(ws + 142606336);  // 8388608 B
  unsigned short* Kb  = (unsigned short*)(ws + 150994944);  // 4194304 B
  unsigned short* VT  = (unsigned short*)(ws + 155189248);  // 4194304 B

  // conversions
  cvt_bf16<<<2048, 256, 0, stream>>>(X, Xbf, (B_ * S_ * E_) / 4);
  addcvt_bf16<<<1024, 256, 0, stream>>>(Kp, Cal, Kb, (H_ * M_ * DH_) / 4);
  transpose_cvt<<<dim3(E_ / 64, E_ / 64, 1), 256, 0, stream>>>(Wq, WqT, E_, H_ * DH_);
  transpose_cvt<<<dim3(E_ / 64, E_ / 64, 1), 256, 0, stream>>>(Wd, WdT, H_ * DH_, E_);
  transpose_cvt<<<dim3(DH_ / 64, M_ / 64, H_), 256, 0, stream>>>(V, VT, M_, DH_);

  // Q projection: (B*S, E) x (E, H*Dh) -> Q bf16 (B,H,S,Dh)
  gemm_bt<0><<<dim3((H_ * DH_) / 128, (B_ * S_) / 128), 256, 0, stream>>>(
      Xbf, WqT, bq, Qb, B_ * S_, H_ * DH_, E_);

  // fused attention -> Ob bf16 (B,S,H*Dh)
  attn_kernel<<<dim3(S_ / 128, B_ * H_), 256, 0, stream>>>(Qb, Kb, VT, Ob);

  // dehead: (B*S, H*Dh) x (H*Dh, E) -> f32 out
  gemm_bt<1><<<dim3(E_ / 128, (B_ * S_) / 128), 256, 0, stream>>>(
      Ob, WdT, bd, (float*)d_out, B_ * S_, E_, H_ * DH_);
}

// Round 2
// 642.203 us; speedup vs baseline: 1.8531x; 1.8531x over previous
//
#include <hip/hip_runtime.h>
#include <stdint.h>

#define B_ 8
#define S_ 2048
#define E_ 2048
#define H_ 16
#define DH_ 128
#define M_ 1024

typedef float f32x4 __attribute__((ext_vector_type(4)));
typedef __bf16 bf16x8 __attribute__((ext_vector_type(8)));
typedef unsigned short ushort8 __attribute__((ext_vector_type(8)));
typedef unsigned short ushort4v __attribute__((ext_vector_type(4)));
typedef float float4v __attribute__((ext_vector_type(4)));

static __device__ __forceinline__ unsigned short f2bf(float f) {
  unsigned int u = __builtin_bit_cast(unsigned int, f);
  u += 0x7fffu + ((u >> 16) & 1u);
  return (unsigned short)(u >> 16);
}

static __device__ __forceinline__ f32x4 mfma16(ushort8 a, ushort8 b, f32x4 c) {
  return __builtin_amdgcn_mfma_f32_16x16x32_bf16(
      __builtin_bit_cast(bf16x8, a), __builtin_bit_cast(bf16x8, b), c, 0, 0, 0);
}

static __device__ __forceinline__ void gload_lds16(const void* g, void* l) {
  __builtin_amdgcn_global_load_lds(
      (const __attribute__((address_space(1))) unsigned int*)g,
      (__attribute__((address_space(3))) unsigned int*)l, 16, 0, 0);
}

// ---------------- conversion kernels ----------------

__global__ void cvt_bf16(const float* __restrict__ in, unsigned short* __restrict__ out, int n4) {
  int i = blockIdx.x * blockDim.x + threadIdx.x;
  int stride = gridDim.x * blockDim.x;
  for (; i < n4; i += stride) {
    float4v v = ((const float4v*)in)[i];
    ushort4v o;
    o[0] = f2bf(v[0]); o[1] = f2bf(v[1]); o[2] = f2bf(v[2]); o[3] = f2bf(v[3]);
    ((ushort4v*)out)[i] = o;
  }
}

__global__ void addcvt_bf16(const float* __restrict__ a, const float* __restrict__ b,
                            unsigned short* __restrict__ out, int n4) {
  int i = blockIdx.x * blockDim.x + threadIdx.x;
  int stride = gridDim.x * blockDim.x;
  for (; i < n4; i += stride) {
    float4v va = ((const float4v*)a)[i];
    float4v vb = ((const float4v*)b)[i];
    ushort4v o;
    o[0] = f2bf(va[0] + vb[0]); o[1] = f2bf(va[1] + vb[1]);
    o[2] = f2bf(va[2] + vb[2]); o[3] = f2bf(va[3] + vb[3]);
    ((ushort4v*)out)[i] = o;
  }
}

// batched transpose + f32->bf16: in[z][R][C] -> out[z][C][R]
__global__ __launch_bounds__(256) void transpose_cvt(const float* __restrict__ in,
                                                     unsigned short* __restrict__ out,
                                                     int R, int C) {
  __shared__ float t[64][65];
  const int tx = threadIdx.x & 63, ty = threadIdx.x >> 6;  // ty in 0..3
  const size_t base = (size_t)blockIdx.z * R * C;
  const int r0 = blockIdx.y * 64, c0 = blockIdx.x * 64;
#pragma unroll
  for (int i = 0; i < 64; i += 4)
    t[i + ty][tx] = in[base + (size_t)(r0 + i + ty) * C + (c0 + tx)];
  __syncthreads();
#pragma unroll
  for (int i = 0; i < 64; i += 4)
    out[base + (size_t)(c0 + i + ty) * R + (r0 + tx)] = f2bf(t[tx][i + ty]);
}

// ---------------- GEMM: C = A(M x K) * BT(N x K)^T + bias ----------------
// EPI 0: write bf16 Q*(1/sqrt(E)) in (B,H,S,Dh) layout, bias = bq (flat H*Dh)
// EPI 1: write f32 out row-major (M x N), bias = bd (flat N)
template <int EPI>
__global__ __launch_bounds__(256) void gemm_bt(const unsigned short* __restrict__ A,
                                               const unsigned short* __restrict__ BT,
                                               const float* __restrict__ bias,
                                               void* __restrict__ Cout,
                                               int Mdim, int Ndim, int Kdim) {
  __shared__ __align__(16) unsigned short a_sm[128 * 64];
  __shared__ __align__(16) unsigned short b_sm[128 * 64];
  const int tid = threadIdx.x;
  const int w = tid >> 6, lane = tid & 63;
  const int l16 = lane & 15, l4 = lane >> 4;
  const int wr = w >> 1, wc = w & 1;
  const int m0 = blockIdx.y << 7, n0 = blockIdx.x << 7;

  f32x4 acc[4][4];
#pragma unroll
  for (int i = 0; i < 4; ++i)
#pragma unroll
    for (int j = 0; j < 4; ++j) acc[i][j] = (f32x4)(0.f);

  const int nkt = Kdim >> 6;
  for (int kt = 0; kt < nkt; ++kt) {
    const unsigned short* Ak = A + (size_t)m0 * Kdim + kt * 64;
    const unsigned short* Bk = BT + (size_t)n0 * Kdim + kt * 64;
#pragma unroll
    for (int i = 0; i < 4; ++i) {
      const int c = i * 4 + w;
      const int row = c * 8 + (lane >> 3);
      const int col = (lane & 7) * 8;
      gload_lds16(Ak + (size_t)row * Kdim + col, &a_sm[c * 512 + lane * 8]);
      gload_lds16(Bk + (size_t)row * Kdim + col, &b_sm[c * 512 + lane * 8]);
    }
    __syncthreads();
#pragma unroll
    for (int kk = 0; kk < 2; ++kk) {
      ushort8 af[4], bf[4];
#pragma unroll
      for (int f = 0; f < 4; ++f) {
        af[f] = *(const ushort8*)&a_sm[(wr * 64 + f * 16 + l16) * 64 + kk * 32 + l4 * 8];
        bf[f] = *(const ushort8*)&b_sm[(wc * 64 + f * 16 + l16) * 64 + kk * 32 + l4 * 8];
      }
#pragma unroll
      for (int fr = 0; fr < 4; ++fr)
#pragma unroll
        for (int fc = 0; fc < 4; ++fc)
          acc[fr][fc] = mfma16(af[fr], bf[fc], acc[fr][fc]);
    }
    __syncthreads();
  }

#pragma unroll
  for (int fr = 0; fr < 4; ++fr) {
    const int mb = m0 + wr * 64 + fr * 16 + l4 * 4;
#pragma unroll
    for (int fc = 0; fc < 4; ++fc) {
      const int n = n0 + wc * 64 + fc * 16 + l16;
      const float bv = bias[n];
#pragma unroll
      for (int r = 0; r < 4; ++r) {
        const float v = acc[fr][fc][r] + bv;
        const int m = mb + r;
        if (EPI == 0) {
          const int b = m >> 11, s = m & 2047, h = n >> 7, d = n & 127;
          ((unsigned short*)Cout)[(((size_t)(b * 16 + h) << 11) + s) * 128 + d] =
              f2bf(v * 0.022097086912079608f);  // pre-scale Q by 1/sqrt(E)
        } else {
          ((float*)Cout)[(size_t)m * Ndim + n] = v;
        }
      }
    }
  }
}

// ---------------- fused attention (softmax-free-max, LDS-staged K/V) ----------------
// grid: (B*H, S/128); block 256 (4 waves x 32 rows). wgid%8 == bh%8 -> per-head XCD affinity.
__global__ __launch_bounds__(256) void attn_kernel(const unsigned short* __restrict__ Qb,
                                                   const unsigned short* __restrict__ Kb,
                                                   const unsigned short* __restrict__ VT,
                                                   unsigned short* __restrict__ Ob) {
  const int bh = blockIdx.x, b = bh >> 4, h = bh & 15;
  const int s0 = blockIdx.y << 7;
  const int tid = threadIdx.x, w = tid >> 6, lane = tid & 63;
  const int l16 = lane & 15, l4 = lane >> 4;
  const int sw = s0 + w * 32;

  // K chunk: [32 m][128 d], XOR-swizzled in 16B granules: granule g holds
  //   K[g>>4][((g&15)^( (g>>4)&7 ))*8 .. +8]
  // V chunk: [128 d][32 m]: granule g holds VT[g>>2][((g&3)^((g>>2)&3))*8 .. +8]
  __shared__ __align__(16) unsigned short k_sm[2][32 * 128];
  __shared__ __align__(16) unsigned short v_sm[2][128 * 32];
  __shared__ __align__(16) unsigned short p_lds[4][32][40];  // pad 40 shorts: 80B rows (16B-aligned)

  const unsigned short* Kh = Kb + (size_t)h * M_ * DH_;
  const unsigned short* Vh = VT + (size_t)h * DH_ * M_;

  // Q fragments (pre-scaled by 1/sqrt(E) in GEMM1 epilogue)
  ushort8 aq[2][4];
  {
    const unsigned short* Qbase = Qb + ((size_t)(b * 16 + h) * S_ + sw) * DH_;
#pragma unroll
    for (int rb = 0; rb < 2; ++rb) {
      const unsigned short* qrow = Qbase + (size_t)(rb * 16 + l16) * DH_ + l4 * 8;
#pragma unroll
      for (int kk = 0; kk < 4; ++kk) aq[rb][kk] = *(const ushort8*)(qrow + kk * 32);
    }
  }

  float lsum[2][4];
  f32x4 o_acc[2][8];
#pragma unroll
  for (int rb = 0; rb < 2; ++rb) {
#pragma unroll
    for (int r = 0; r < 4; ++r) lsum[rb][r] = 0.f;
#pragma unroll
    for (int nc = 0; nc < 8; ++nc) o_acc[rb][nc] = (f32x4)(0.f);
  }

#define STAGE(bufidx, mc_)                                                              \
  do {                                                                                  \
    const int m0s = (mc_) << 5;                                                         \
    unsigned short* kdst = &k_sm[bufidx][0];                                            \
    unsigned short* vdst = &v_sm[bufidx][0];                                            \
    _Pragma("unroll") for (int i_ = 0; i_ < 2; ++i_) {                                  \
      const int g_ = i_ * 256 + tid;                                                    \
      const int kr = g_ >> 4, kc = g_ & 15;                                             \
      gload_lds16(Kh + (size_t)(m0s + kr) * DH_ + ((kc ^ (kr & 7)) << 3), kdst + g_ * 8); \
      const int vd = g_ >> 2, vc = g_ & 3;                                              \
      gload_lds16(Vh + (size_t)vd * M_ + m0s + ((vc ^ (vd & 3)) << 3), vdst + g_ * 8);  \
    }                                                                                   \
  } while (0)

  int cur = 0;
  STAGE(0, 0);
  __syncthreads();

  for (int mc = 0; mc < 32; ++mc) {
    if (mc < 31) STAGE(cur ^ 1, mc + 1);

    // ---- QK^T: sa[rb][nc], rows = s (l4*4+r), cols = m (nc*16+l16) ----
    f32x4 sa[2][2];
#pragma unroll
    for (int rb = 0; rb < 2; ++rb)
#pragma unroll
      for (int nc = 0; nc < 2; ++nc) sa[rb][nc] = (f32x4)(0.f);

#pragma unroll
    for (int nc = 0; nc < 2; ++nc) {
      const int row = nc * 16 + l16;
      const unsigned short* kbase = &k_sm[cur][row * DH_];
#pragma unroll
      for (int kk = 0; kk < 4; ++kk) {
        const int gran = (kk * 4 + l4) ^ (row & 7);
        ushort8 bk = *(const ushort8*)(kbase + gran * 8);
        sa[0][nc] = mfma16(aq[0][kk], bk, sa[0][nc]);
        sa[1][nc] = mfma16(aq[1][kk], bk, sa[1][nc]);
      }
    }

    // ---- exp (no max subtraction: scores are O(0.1)), accumulate denom ----
#pragma unroll
    for (int rb = 0; rb < 2; ++rb)
#pragma unroll
      for (int nc = 0; nc < 2; ++nc)
#pragma unroll
        for (int r = 0; r < 4; ++r) {
          const float p = __expf(sa[rb][nc][r]);
          lsum[rb][r] += p;
          p_lds[w][rb * 16 + l4 * 4 + r][nc * 16 + l16] = f2bf(p);
        }

    // ---- PV: A = P rows (s), B = VT rows (d), k-dim = 32 m ----
    ushort8 pf[2];
#pragma unroll
    for (int rb = 0; rb < 2; ++rb)
      pf[rb] = *(const ushort8*)&p_lds[w][rb * 16 + l16][l4 * 8];
#pragma unroll
    for (int nc = 0; nc < 8; ++nc) {
      const int row = nc * 16 + l16;
      const int gran = l4 ^ (row & 3);
      ushort8 bv = *(const ushort8*)&v_sm[cur][row * 32 + gran * 8];
      o_acc[0][nc] = mfma16(pf[0], bv, o_acc[0][nc]);
      o_acc[1][nc] = mfma16(pf[1], bv, o_acc[1][nc]);
    }

    __syncthreads();
    cur ^= 1;
  }
#undef STAGE

  // ---- epilogue: reduce denominators once, normalize, store ----
#pragma unroll
  for (int rb = 0; rb < 2; ++rb)
#pragma unroll
    for (int r = 0; r < 4; ++r) {
      float s = lsum[rb][r];
      s += __shfl_xor(s, 1, 64);
      s += __shfl_xor(s, 2, 64);
      s += __shfl_xor(s, 4, 64);
      s += __shfl_xor(s, 8, 64);
      const float inv = 1.0f / s;
      const int srow = sw + rb * 16 + l4 * 4 + r;
      unsigned short* orow = Ob + ((size_t)b * S_ + srow) * (H_ * DH_) + h * DH_;
#pragma unroll
      for (int nc = 0; nc < 8; ++nc)
        orow[nc * 16 + l16] = f2bf(o_acc[rb][nc][r] * inv);
    }
}

// ---------------- launcher ----------------

extern "C" void kernel_launch(void* const* d_in, const int* in_sizes, int n_in,
                              void* d_out, int out_size, void* d_ws, size_t ws_size,
                              hipStream_t stream) {
  const float* X   = (const float*)d_in[0];
  const float* Wq  = (const float*)d_in[1];
  const float* bq  = (const float*)d_in[2];
  const float* Kp  = (const float*)d_in[3];
  const float* Cal = (const float*)d_in[4];
  const float* V   = (const float*)d_in[5];
  const float* Wd  = (const float*)d_in[6];
  const float* bd  = (const float*)d_in[7];

  char* ws = (char*)d_ws;
  unsigned short* Xbf = (unsigned short*)(ws + 0);          // 67108864 B (reused as Ob)
  unsigned short* Ob  = Xbf;                                 // alias: X dead after GEMM1
  unsigned short* Qb  = (unsigned short*)(ws + 67108864);   // 67108864 B
  unsigned short* WqT = (unsigned short*)(ws + 134217728);  // 8388608 B
  unsigned short* WdT = (unsigned short*)(ws + 142606336);  // 8388608 B
  unsigned short* Kb  = (unsigned short*)(ws + 150994944);  // 4194304 B
  unsigned short* VT  = (unsigned short*)(ws + 155189248);  // 4194304 B

  // conversions
  cvt_bf16<<<2048, 256, 0, stream>>>(X, Xbf, (B_ * S_ * E_) / 4);
  addcvt_bf16<<<1024, 256, 0, stream>>>(Kp, Cal, Kb, (H_ * M_ * DH_) / 4);
  transpose_cvt<<<dim3(E_ / 64, E_ / 64, 1), 256, 0, stream>>>(Wq, WqT, E_, H_ * DH_);
  transpose_cvt<<<dim3(E_ / 64, E_ / 64, 1), 256, 0, stream>>>(Wd, WdT, H_ * DH_, E_);
  transpose_cvt<<<dim3(DH_ / 64, M_ / 64, H_), 256, 0, stream>>>(V, VT, M_, DH_);

  // Q projection: (B*S, E) x (E, H*Dh) -> Q bf16 (B,H,S,Dh), pre-scaled
  gemm_bt<0><<<dim3((H_ * DH_) / 128, (B_ * S_) / 128), 256, 0, stream>>>(
      Xbf, WqT, bq, Qb, B_ * S_, H_ * DH_, E_);

  // fused attention -> Ob bf16 (B,S,H*Dh)
  attn_kernel<<<dim3(B_ * H_, S_ / 128), 256, 0, stream>>>(Qb, Kb, VT, Ob);

  // dehead: (B*S, H*Dh) x (H*Dh, E) -> f32 out
  gemm_bt<1><<<dim3(E_ / 128, (B_ * S_) / 128), 256, 0, stream>>>(
      Ob, WdT, bd, (float*)d_out, B_ * S_, E_, H_ * DH_);
}

// Round 3
// 606.537 us; speedup vs baseline: 1.9621x; 1.0588x over previous
//
#include <hip/hip_runtime.h>
#include <stdint.h>

#define B_ 8
#define S_ 2048
#define E_ 2048
#define H_ 16
#define DH_ 128
#define M_ 1024

typedef float f32x4 __attribute__((ext_vector_type(4)));
typedef __bf16 bf16x8 __attribute__((ext_vector_type(8)));
typedef unsigned short ushort8 __attribute__((ext_vector_type(8)));
typedef unsigned short ushort4v __attribute__((ext_vector_type(4)));
typedef float float4v __attribute__((ext_vector_type(4)));

static __device__ __forceinline__ unsigned short f2bf(float f) {
  unsigned int u = __builtin_bit_cast(unsigned int, f);
  u += 0x7fffu + ((u >> 16) & 1u);
  return (unsigned short)(u >> 16);
}

static __device__ __forceinline__ float exp2f_fast(float x) {
#if __has_builtin(__builtin_amdgcn_exp2f)
  return __builtin_amdgcn_exp2f(x);
#else
  return __expf(x * 0.6931471805599453f);
#endif
}

static __device__ __forceinline__ f32x4 mfma16(ushort8 a, ushort8 b, f32x4 c) {
  return __builtin_amdgcn_mfma_f32_16x16x32_bf16(
      __builtin_bit_cast(bf16x8, a), __builtin_bit_cast(bf16x8, b), c, 0, 0, 0);
}

static __device__ __forceinline__ void gload_lds16(const void* g, void* l) {
  __builtin_amdgcn_global_load_lds(
      (const __attribute__((address_space(1))) unsigned int*)g,
      (__attribute__((address_space(3))) unsigned int*)l, 16, 0, 0);
}

// ---------------- conversion kernels ----------------

__global__ void cvt_bf16(const float* __restrict__ in, unsigned short* __restrict__ out, int n4) {
  int i = blockIdx.x * blockDim.x + threadIdx.x;
  int stride = gridDim.x * blockDim.x;
  for (; i < n4; i += stride) {
    float4v v = ((const float4v*)in)[i];
    ushort4v o;
    o[0] = f2bf(v[0]); o[1] = f2bf(v[1]); o[2] = f2bf(v[2]); o[3] = f2bf(v[3]);
    ((ushort4v*)out)[i] = o;
  }
}

__global__ void addcvt_bf16(const float* __restrict__ a, const float* __restrict__ b,
                            unsigned short* __restrict__ out, int n4) {
  int i = blockIdx.x * blockDim.x + threadIdx.x;
  int stride = gridDim.x * blockDim.x;
  for (; i < n4; i += stride) {
    float4v va = ((const float4v*)a)[i];
    float4v vb = ((const float4v*)b)[i];
    ushort4v o;
    o[0] = f2bf(va[0] + vb[0]); o[1] = f2bf(va[1] + vb[1]);
    o[2] = f2bf(va[2] + vb[2]); o[3] = f2bf(va[3] + vb[3]);
    ((ushort4v*)out)[i] = o;
  }
}

// batched transpose + f32->bf16: in[z][R][C] -> out[z][C][R]
__global__ __launch_bounds__(256) void transpose_cvt(const float* __restrict__ in,
                                                     unsigned short* __restrict__ out,
                                                     int R, int C) {
  __shared__ float t[64][65];
  const int tx = threadIdx.x & 63, ty = threadIdx.x >> 6;  // ty in 0..3
  const size_t base = (size_t)blockIdx.z * R * C;
  const int r0 = blockIdx.y * 64, c0 = blockIdx.x * 64;
#pragma unroll
  for (int i = 0; i < 64; i += 4)
    t[i + ty][tx] = in[base + (size_t)(r0 + i + ty) * C + (c0 + tx)];
  __syncthreads();
#pragma unroll
  for (int i = 0; i < 64; i += 4)
    out[base + (size_t)(c0 + i + ty) * R + (r0 + tx)] = f2bf(t[tx][i + ty]);
}

// ---------------- GEMM: C = A(M x K) * BT(N x K)^T + bias ----------------
// EPI 0: write bf16 Q*(log2e/sqrt(E)) in (B,H,S,Dh) layout, bias = bq (flat H*Dh)
// EPI 1: write f32 out row-major (M x N), bias = bd (flat N)
template <int EPI>
__global__ __launch_bounds__(256) void gemm_bt(const unsigned short* __restrict__ A,
                                               const unsigned short* __restrict__ BT,
                                               const float* __restrict__ bias,
                                               void* __restrict__ Cout,
                                               int Mdim, int Ndim, int Kdim) {
  __shared__ __align__(16) unsigned short a_sm[128 * 64];
  __shared__ __align__(16) unsigned short b_sm[128 * 64];
  const int tid = threadIdx.x;
  const int w = tid >> 6, lane = tid & 63;
  const int l16 = lane & 15, l4 = lane >> 4;
  const int wr = w >> 1, wc = w & 1;
  const int m0 = blockIdx.y << 7, n0 = blockIdx.x << 7;

  f32x4 acc[4][4];
#pragma unroll
  for (int i = 0; i < 4; ++i)
#pragma unroll
    for (int j = 0; j < 4; ++j) acc[i][j] = (f32x4)(0.f);

  const int nkt = Kdim >> 6;
  for (int kt = 0; kt < nkt; ++kt) {
    const unsigned short* Ak = A + (size_t)m0 * Kdim + kt * 64;
    const unsigned short* Bk = BT + (size_t)n0 * Kdim + kt * 64;
#pragma unroll
    for (int i = 0; i < 4; ++i) {
      const int c = i * 4 + w;
      const int row = c * 8 + (lane >> 3);
      const int col = (lane & 7) * 8;
      gload_lds16(Ak + (size_t)row * Kdim + col, &a_sm[c * 512 + lane * 8]);
      gload_lds16(Bk + (size_t)row * Kdim + col, &b_sm[c * 512 + lane * 8]);
    }
    __syncthreads();
#pragma unroll
    for (int kk = 0; kk < 2; ++kk) {
      ushort8 af[4], bf[4];
#pragma unroll
      for (int f = 0; f < 4; ++f) {
        af[f] = *(const ushort8*)&a_sm[(wr * 64 + f * 16 + l16) * 64 + kk * 32 + l4 * 8];
        bf[f] = *(const ushort8*)&b_sm[(wc * 64 + f * 16 + l16) * 64 + kk * 32 + l4 * 8];
      }
#pragma unroll
      for (int fr = 0; fr < 4; ++fr)
#pragma unroll
        for (int fc = 0; fc < 4; ++fc)
          acc[fr][fc] = mfma16(af[fr], bf[fc], acc[fr][fc]);
    }
    __syncthreads();
  }

#pragma unroll
  for (int fr = 0; fr < 4; ++fr) {
    const int mb = m0 + wr * 64 + fr * 16 + l4 * 4;
#pragma unroll
    for (int fc = 0; fc < 4; ++fc) {
      const int n = n0 + wc * 64 + fc * 16 + l16;
      const float bv = bias[n];
#pragma unroll
      for (int r = 0; r < 4; ++r) {
        const float v = acc[fr][fc][r] + bv;
        const int m = mb + r;
        if (EPI == 0) {
          const int b = m >> 11, s = m & 2047, h = n >> 7, d = n & 127;
          // pre-scale Q by log2(e)/sqrt(E) so attn uses exp2 directly
          ((unsigned short*)Cout)[(((size_t)(b * 16 + h) << 11) + s) * 128 + d] =
              f2bf(v * 0.031879358f);
        } else {
          ((float*)Cout)[(size_t)m * Ndim + n] = v;
        }
      }
    }
  }
}

// ---------------- fused attention (no-max softmax, LDS-staged K/V) ----------------
// grid: (B*H, S/128); block 256 (4 waves x 32 rows). wgid%8 == bh%8 -> per-head XCD affinity.
__global__ __launch_bounds__(256) void attn_kernel(const unsigned short* __restrict__ Qb,
                                                   const unsigned short* __restrict__ Kb,
                                                   const unsigned short* __restrict__ VT,
                                                   unsigned short* __restrict__ Ob) {
  const int bh = blockIdx.x, b = bh >> 4, h = bh & 15;
  const int s0 = blockIdx.y << 7;
  const int tid = threadIdx.x, w = tid >> 6, lane = tid & 63;
  const int l16 = lane & 15, l4 = lane >> 4;
  const int sw = s0 + w * 32;

  __shared__ __align__(16) unsigned short k_sm[2][32 * 128];
  __shared__ __align__(16) unsigned short v_sm[2][128 * 32];
  __shared__ __align__(16) unsigned short p_lds[4][32][40];  // 80B row stride

  const unsigned short* Kh = Kb + (size_t)h * M_ * DH_;
  const unsigned short* Vh = VT + (size_t)h * DH_ * M_;

  // Q fragments (pre-scaled by log2e/sqrt(E) in GEMM1 epilogue)
  ushort8 aq[2][4];
  {
    const unsigned short* Qbase = Qb + ((size_t)(b * 16 + h) * S_ + sw) * DH_;
#pragma unroll
    for (int rb = 0; rb < 2; ++rb) {
      const unsigned short* qrow = Qbase + (size_t)(rb * 16 + l16) * DH_ + l4 * 8;
#pragma unroll
      for (int kk = 0; kk < 4; ++kk) aq[rb][kk] = *(const ushort8*)(qrow + kk * 32);
    }
  }

  float lsum[2][4];
  f32x4 o_acc[2][8];
#pragma unroll
  for (int rb = 0; rb < 2; ++rb) {
#pragma unroll
    for (int r = 0; r < 4; ++r) lsum[rb][r] = 0.f;
#pragma unroll
    for (int nc = 0; nc < 8; ++nc) o_acc[rb][nc] = (f32x4)(0.f);
  }

#define STAGE(bufidx, mc_)                                                              \
  do {                                                                                  \
    const int m0s = (mc_) << 5;                                                         \
    unsigned short* kdst = &k_sm[bufidx][0];                                            \
    unsigned short* vdst = &v_sm[bufidx][0];                                            \
    _Pragma("unroll") for (int i_ = 0; i_ < 2; ++i_) {                                  \
      const int g_ = i_ * 256 + tid;                                                    \
      const int kr = g_ >> 4, kc = g_ & 15;                                             \
      gload_lds16(Kh + (size_t)(m0s + kr) * DH_ + ((kc ^ (kr & 7)) << 3), kdst + g_ * 8); \
      const int vd = g_ >> 2, vc = g_ & 3;                                              \
      gload_lds16(Vh + (size_t)vd * M_ + m0s + ((vc ^ (vd & 3)) << 3), vdst + g_ * 8);  \
    }                                                                                   \
  } while (0)

  int cur = 0;
  STAGE(0, 0);
  __syncthreads();

  for (int mc = 0; mc < 32; ++mc) {
    if (mc < 31) STAGE(cur ^ 1, mc + 1);

    // ---- QK^T: sa[rb][nc], rows = s (l4*4+r), cols = m (nc*16+l16) ----
    f32x4 sa[2][2];
#pragma unroll
    for (int rb = 0; rb < 2; ++rb)
#pragma unroll
      for (int nc = 0; nc < 2; ++nc) sa[rb][nc] = (f32x4)(0.f);

    __builtin_amdgcn_s_setprio(1);
#pragma unroll
    for (int nc = 0; nc < 2; ++nc) {
      const int row = nc * 16 + l16;
      const unsigned short* kbase = &k_sm[cur][row * DH_];
#pragma unroll
      for (int kk = 0; kk < 4; ++kk) {
        const int gran = (kk * 4 + l4) ^ (row & 7);
        ushort8 bk = *(const ushort8*)(kbase + gran * 8);
        sa[0][nc] = mfma16(aq[0][kk], bk, sa[0][nc]);
        sa[1][nc] = mfma16(aq[1][kk], bk, sa[1][nc]);
      }
    }
    __builtin_amdgcn_s_setprio(0);

    // ---- p = exp2(s) (Q pre-scaled; no max subtraction), pack+store via cvt_pk ----
#pragma unroll
    for (int rb = 0; rb < 2; ++rb) {
#pragma unroll
      for (int r = 0; r < 4; ++r) {
        const float p0 = exp2f_fast(sa[rb][0][r]);
        const float p1 = exp2f_fast(sa[rb][1][r]);
        lsum[rb][r] += p0 + p1;
        unsigned pu;
        asm("v_cvt_pk_bf16_f32 %0, %1, %2" : "=v"(pu) : "v"(p0), "v"(p1));
        unsigned paddr = (unsigned)(size_t)&p_lds[w][rb * 16 + l4 * 4 + r][l16];
        asm volatile("ds_write_b16 %0, %1\n\t"
                     "ds_write_b16_d16_hi %0, %1 offset:32"
                     :: "v"(paddr), "v"(pu) : "memory");
      }
    }

    // ---- PV: A = P rows (s), B = VT rows (d), k-dim = 32 m ----
    ushort8 pf[2];
#pragma unroll
    for (int rb = 0; rb < 2; ++rb)
      pf[rb] = *(const ushort8*)&p_lds[w][rb * 16 + l16][l4 * 8];
    __builtin_amdgcn_s_setprio(1);
#pragma unroll
    for (int nc = 0; nc < 8; ++nc) {
      const int row = nc * 16 + l16;
      const int gran = l4 ^ (row & 3);
      ushort8 bv = *(const ushort8*)&v_sm[cur][row * 32 + gran * 8];
      o_acc[0][nc] = mfma16(pf[0], bv, o_acc[0][nc]);
      o_acc[1][nc] = mfma16(pf[1], bv, o_acc[1][nc]);
    }
    __builtin_amdgcn_s_setprio(0);

    __syncthreads();
    cur ^= 1;
  }
#undef STAGE

  // ---- epilogue: reduce denominators once, normalize, store ----
#pragma unroll
  for (int rb = 0; rb < 2; ++rb)
#pragma unroll
    for (int r = 0; r < 4; ++r) {
      float s = lsum[rb][r];
      s += __shfl_xor(s, 1, 64);
      s += __shfl_xor(s, 2, 64);
      s += __shfl_xor(s, 4, 64);
      s += __shfl_xor(s, 8, 64);
      const float inv = 1.0f / s;
      const int srow = sw + rb * 16 + l4 * 4 + r;
      unsigned short* orow = Ob + ((size_t)b * S_ + srow) * (H_ * DH_) + h * DH_;
#pragma unroll
      for (int nc = 0; nc < 8; ++nc)
        orow[nc * 16 + l16] = f2bf(o_acc[rb][nc][r] * inv);
    }
}

// ---------------- launcher ----------------

extern "C" void kernel_launch(void* const* d_in, const int* in_sizes, int n_in,
                              void* d_out, int out_size, void* d_ws, size_t ws_size,
                              hipStream_t stream) {
  const float* X   = (const float*)d_in[0];
  const float* Wq  = (const float*)d_in[1];
  const float* bq  = (const float*)d_in[2];
  const float* Kp  = (const float*)d_in[3];
  const float* Cal = (const float*)d_in[4];
  const float* V   = (const float*)d_in[5];
  const float* Wd  = (const float*)d_in[6];
  const float* bd  = (const float*)d_in[7];

  char* ws = (char*)d_ws;
  unsigned short* Xbf = (unsigned short*)(ws + 0);          // 67108864 B (reused as Ob)
  unsigned short* Ob  = Xbf;                                 // alias: X dead after GEMM1
  unsigned short* Qb  = (unsigned short*)(ws + 67108864);   // 67108864 B
  unsigned short* WqT = (unsigned short*)(ws + 134217728);  // 8388608 B
  unsigned short* WdT = (unsigned short*)(ws + 142606336);  // 8388608 B
  unsigned short* Kb  = (unsigned short*)(ws + 150994944);  // 4194304 B
  unsigned short* VT  = (unsigned short*)(ws + 155189248);  // 4194304 B

  // conversions
  cvt_bf16<<<2048, 256, 0, stream>>>(X, Xbf, (B_ * S_ * E_) / 4);
  addcvt_bf16<<<1024, 256, 0, stream>>>(Kp, Cal, Kb, (H_ * M_ * DH_) / 4);
  transpose_cvt<<<dim3(E_ / 64, E_ / 64, 1), 256, 0, stream>>>(Wq, WqT, E_, H_ * DH_);
  transpose_cvt<<<dim3(E_ / 64, E_ / 64, 1), 256, 0, stream>>>(Wd, WdT, H_ * DH_, E_);
  transpose_cvt<<<dim3(DH_ / 64, M_ / 64, H_), 256, 0, stream>>>(V, VT, M_, DH_);

  // Q projection: (B*S, E) x (E, H*Dh) -> Q bf16 (B,H,S,Dh), pre-scaled
  gemm_bt<0><<<dim3((H_ * DH_) / 128, (B_ * S_) / 128), 256, 0, stream>>>(
      Xbf, WqT, bq, Qb, B_ * S_, H_ * DH_, E_);

  // fused attention -> Ob bf16 (B,S,H*Dh)
  attn_kernel<<<dim3(B_ * H_, S_ / 128), 256, 0, stream>>>(Qb, Kb, VT, Ob);

  // dehead: (B*S, H*Dh) x (H*Dh, E) -> f32 out
  gemm_bt<1><<<dim3(E_ / 128, (B_ * S_) / 128), 256, 0, stream>>>(
      Ob, WdT, bd, (float*)d_out, B_ * S_, E_, H_ * DH_);
}

// Round 4
// 587.568 us; speedup vs baseline: 2.0254x; 1.0323x over previous
//
#include <hip/hip_runtime.h>
#include <stdint.h>

#define B_ 8
#define S_ 2048
#define E_ 2048
#define H_ 16
#define DH_ 128
#define M_ 1024
#define K_ 2048

typedef float f32x4 __attribute__((ext_vector_type(4)));
typedef __bf16 bf16x8 __attribute__((ext_vector_type(8)));
typedef unsigned short ushort8 __attribute__((ext_vector_type(8)));
typedef unsigned short ushort4v __attribute__((ext_vector_type(4)));
typedef float float4v __attribute__((ext_vector_type(4)));

static __device__ __forceinline__ unsigned short f2bf(float f) {
  unsigned int u = __builtin_bit_cast(unsigned int, f);
  u += 0x7fffu + ((u >> 16) & 1u);
  return (unsigned short)(u >> 16);
}

static __device__ __forceinline__ float exp2f_fast(float x) {
#if __has_builtin(__builtin_amdgcn_exp2f)
  return __builtin_amdgcn_exp2f(x);
#else
  return __expf(x * 0.6931471805599453f);
#endif
}

static __device__ __forceinline__ f32x4 mfma16(ushort8 a, ushort8 b, f32x4 c) {
  return __builtin_amdgcn_mfma_f32_16x16x32_bf16(
      __builtin_bit_cast(bf16x8, a), __builtin_bit_cast(bf16x8, b), c, 0, 0, 0);
}

static __device__ __forceinline__ void gload_lds16(const void* g, void* l) {
  __builtin_amdgcn_global_load_lds(
      (const __attribute__((address_space(1))) unsigned int*)g,
      (__attribute__((address_space(3))) unsigned int*)l, 16, 0, 0);
}

// ---------------- conversion kernels ----------------

__global__ void cvt_bf16(const float* __restrict__ in, unsigned short* __restrict__ out, int n4) {
  int i = blockIdx.x * blockDim.x + threadIdx.x;
  int stride = gridDim.x * blockDim.x;
  for (; i < n4; i += stride) {
    float4v v = ((const float4v*)in)[i];
    ushort4v o;
    o[0] = f2bf(v[0]); o[1] = f2bf(v[1]); o[2] = f2bf(v[2]); o[3] = f2bf(v[3]);
    ((ushort4v*)out)[i] = o;
  }
}

__global__ void addcvt_bf16(const float* __restrict__ a, const float* __restrict__ b,
                            unsigned short* __restrict__ out, int n4) {
  int i = blockIdx.x * blockDim.x + threadIdx.x;
  int stride = gridDim.x * blockDim.x;
  for (; i < n4; i += stride) {
    float4v va = ((const float4v*)a)[i];
    float4v vb = ((const float4v*)b)[i];
    ushort4v o;
    o[0] = f2bf(va[0] + vb[0]); o[1] = f2bf(va[1] + vb[1]);
    o[2] = f2bf(va[2] + vb[2]); o[3] = f2bf(va[3] + vb[3]);
    ((ushort4v*)out)[i] = o;
  }
}

// batched transpose + f32->bf16: in[z][R][C] -> out[z][C][R]
__global__ __launch_bounds__(256) void transpose_cvt(const float* __restrict__ in,
                                                     unsigned short* __restrict__ out,
                                                     int R, int C) {
  __shared__ float t[64][65];
  const int tx = threadIdx.x & 63, ty = threadIdx.x >> 6;  // ty in 0..3
  const size_t base = (size_t)blockIdx.z * R * C;
  const int r0 = blockIdx.y * 64, c0 = blockIdx.x * 64;
#pragma unroll
  for (int i = 0; i < 64; i += 4)
    t[i + ty][tx] = in[base + (size_t)(r0 + i + ty) * C + (c0 + tx)];
  __syncthreads();
#pragma unroll
  for (int i = 0; i < 64; i += 4)
    out[base + (size_t)(c0 + i + ty) * R + (r0 + tx)] = f2bf(t[tx][i + ty]);
}

// ---------------- pipelined GEMM: C = A(16384 x 2048) * BT(2048 x 2048)^T + bias ----
// BM=128, BN=256, BK=64; 8 waves (2M x 4N); 3 LDS buffers, prefetch distance 2,
// counted vmcnt(6) at tile boundaries (raw s_barrier -- no vmcnt(0) drain).
// EPI 0: write bf16 Q*(log2e/sqrt(E)) in (B,H,S,Dh) layout; EPI 1: f32 row-major.
template <int EPI>
__global__ __launch_bounds__(512, 2) void gemm256(const unsigned short* __restrict__ A,
                                                  const unsigned short* __restrict__ BT,
                                                  const float* __restrict__ bias,
                                                  void* __restrict__ Cout) {
  __shared__ __align__(16) unsigned short a_sm[3][128 * 64];
  __shared__ __align__(16) unsigned short b_sm[3][256 * 64];
  const int tid = threadIdx.x;
  const int w = tid >> 6, lane = tid & 63;
  const int l16 = lane & 15, l4 = lane >> 4;
  const int wr = w >> 2, wc = w & 3;  // 2 x 4 wave grid
  // XCD-chunked mapping: xcd owns 16 M-rows x all 8 N-cols, n-inner.
  const int bid = blockIdx.x;
  const int xcd = bid & 7, idx = bid >> 3;       // idx 0..127
  const int m0 = (xcd * 16 + (idx >> 3)) << 7;   // 128-row M tile
  const int n0 = (idx & 7) << 8;                 // 256-col N tile

  f32x4 acc[4][4];
#pragma unroll
  for (int i = 0; i < 4; ++i)
#pragma unroll
    for (int j = 0; j < 4; ++j) acc[i][j] = (f32x4)(0.f);

  // LDS granule-swizzle: slot (row, g) holds global granule g^(row&7) (16B granules).
#define GSTAGE(s, kt)                                                         \
  do {                                                                        \
    const unsigned short* Ak_ = A + (size_t)m0 * K_ + (kt) * 64;              \
    const unsigned short* Bk_ = BT + (size_t)n0 * K_ + (kt) * 64;             \
    _Pragma("unroll") for (int j_ = 0; j_ < 2; ++j_) {                        \
      const int i_ = j_ * 512 + tid;                                          \
      const int r_ = i_ >> 3, g_ = i_ & 7;                                    \
      gload_lds16(Ak_ + (size_t)r_ * K_ + ((g_ ^ (r_ & 7)) << 3),             \
                  &a_sm[s][i_ * 8]);                                          \
    }                                                                         \
    _Pragma("unroll") for (int j_ = 0; j_ < 4; ++j_) {                        \
      const int i_ = j_ * 512 + tid;                                          \
      const int r_ = i_ >> 3, g_ = i_ & 7;                                    \
      gload_lds16(Bk_ + (size_t)r_ * K_ + ((g_ ^ (r_ & 7)) << 3),             \
                  &b_sm[s][i_ * 8]);                                          \
    }                                                                         \
  } while (0)

  // prologue: stage tiles 0 and 1; wait for tile 0 (6 newest may float)
  GSTAGE(0, 0);
  GSTAGE(1, 1);
  __builtin_amdgcn_sched_barrier(0);
  asm volatile("s_waitcnt vmcnt(6)" ::: "memory");
  __builtin_amdgcn_s_barrier();
  __builtin_amdgcn_sched_barrier(0);

  int c0 = 0;
  for (int kt = 0; kt < 32; ++kt) {
    const int c2 = (c0 >= 1) ? c0 - 1 : 2;  // (c0+2)%3
    if (kt < 30) GSTAGE(c2, kt + 2);
    const unsigned short* as = a_sm[c0];
    const unsigned short* bs = b_sm[c0];
#pragma unroll
    for (int ks = 0; ks < 2; ++ks) {
      ushort8 af[4], bfr[4];
#pragma unroll
      for (int mr = 0; mr < 4; ++mr) {
        const int row = wr * 64 + mr * 16 + l16;
        const int gr = (ks * 4 + l4) ^ (row & 7);
        af[mr] = *(const ushort8*)&as[row * 64 + gr * 8];
      }
#pragma unroll
      for (int nr = 0; nr < 4; ++nr) {
        const int row = wc * 64 + nr * 16 + l16;
        const int gr = (ks * 4 + l4) ^ (row & 7);
        bfr[nr] = *(const ushort8*)&bs[row * 64 + gr * 8];
      }
      __builtin_amdgcn_s_setprio(1);
#pragma unroll
      for (int mr = 0; mr < 4; ++mr)
#pragma unroll
        for (int nr = 0; nr < 4; ++nr)
          acc[mr][nr] = mfma16(af[mr], bfr[nr], acc[mr][nr]);
      __builtin_amdgcn_s_setprio(0);
    }
    __builtin_amdgcn_sched_barrier(0);
    if (kt < 30)
      asm volatile("s_waitcnt vmcnt(6)" ::: "memory");  // tile kt+1 landed; kt+2 in flight
    else
      asm volatile("s_waitcnt vmcnt(0)" ::: "memory");  // epilogue drain
    __builtin_amdgcn_s_barrier();
    __builtin_amdgcn_sched_barrier(0);
    c0 = (c0 >= 2) ? 0 : c0 + 1;
  }
#undef GSTAGE

#pragma unroll
  for (int mr = 0; mr < 4; ++mr) {
    const int mb = m0 + wr * 64 + mr * 16 + l4 * 4;
#pragma unroll
    for (int nr = 0; nr < 4; ++nr) {
      const int n = n0 + wc * 64 + nr * 16 + l16;
      const float bv = bias[n];
#pragma unroll
      for (int r = 0; r < 4; ++r) {
        const float v = acc[mr][nr][r] + bv;
        const int m = mb + r;
        if (EPI == 0) {
          const int b = m >> 11, s = m & 2047, h = n >> 7, d = n & 127;
          // pre-scale Q by log2(e)/sqrt(E) so attn uses exp2 directly
          ((unsigned short*)Cout)[(((size_t)(b * 16 + h) << 11) + s) * 128 + d] =
              f2bf(v * 0.031879358f);
        } else {
          ((float*)Cout)[(size_t)m * E_ + n] = v;
        }
      }
    }
  }
}

// ---------------- fused attention (no-max softmax, LDS-staged K/V) ----------------
// grid: (B*H, S/128); block 256 (4 waves x 32 rows). wgid%8 == bh%8 -> per-head XCD affinity.
__global__ __launch_bounds__(256) void attn_kernel(const unsigned short* __restrict__ Qb,
                                                   const unsigned short* __restrict__ Kb,
                                                   const unsigned short* __restrict__ VT,
                                                   unsigned short* __restrict__ Ob) {
  const int bh = blockIdx.x, b = bh >> 4, h = bh & 15;
  const int s0 = blockIdx.y << 7;
  const int tid = threadIdx.x, w = tid >> 6, lane = tid & 63;
  const int l16 = lane & 15, l4 = lane >> 4;
  const int sw = s0 + w * 32;

  __shared__ __align__(16) unsigned short k_sm[2][32 * 128];
  __shared__ __align__(16) unsigned short v_sm[2][128 * 32];
  __shared__ __align__(16) unsigned short p_lds[4][32][40];  // 80B row stride

  const unsigned short* Kh = Kb + (size_t)h * M_ * DH_;
  const unsigned short* Vh = VT + (size_t)h * DH_ * M_;

  // Q fragments (pre-scaled by log2e/sqrt(E) in GEMM1 epilogue)
  ushort8 aq[2][4];
  {
    const unsigned short* Qbase = Qb + ((size_t)(b * 16 + h) * S_ + sw) * DH_;
#pragma unroll
    for (int rb = 0; rb < 2; ++rb) {
      const unsigned short* qrow = Qbase + (size_t)(rb * 16 + l16) * DH_ + l4 * 8;
#pragma unroll
      for (int kk = 0; kk < 4; ++kk) aq[rb][kk] = *(const ushort8*)(qrow + kk * 32);
    }
  }

  float lsum[2][4];
  f32x4 o_acc[2][8];
#pragma unroll
  for (int rb = 0; rb < 2; ++rb) {
#pragma unroll
    for (int r = 0; r < 4; ++r) lsum[rb][r] = 0.f;
#pragma unroll
    for (int nc = 0; nc < 8; ++nc) o_acc[rb][nc] = (f32x4)(0.f);
  }

#define STAGE(bufidx, mc_)                                                              \
  do {                                                                                  \
    const int m0s = (mc_) << 5;                                                         \
    unsigned short* kdst = &k_sm[bufidx][0];                                            \
    unsigned short* vdst = &v_sm[bufidx][0];                                            \
    _Pragma("unroll") for (int i_ = 0; i_ < 2; ++i_) {                                  \
      const int g_ = i_ * 256 + tid;                                                    \
      const int kr = g_ >> 4, kc = g_ & 15;                                             \
      gload_lds16(Kh + (size_t)(m0s + kr) * DH_ + ((kc ^ (kr & 7)) << 3), kdst + g_ * 8); \
      const int vd = g_ >> 2, vc = g_ & 3;                                              \
      gload_lds16(Vh + (size_t)vd * M_ + m0s + ((vc ^ (vd & 3)) << 3), vdst + g_ * 8);  \
    }                                                                                   \
  } while (0)

  int cur = 0;
  STAGE(0, 0);
  __syncthreads();

  for (int mc = 0; mc < 32; ++mc) {
    if (mc < 31) STAGE(cur ^ 1, mc + 1);

    // ---- QK^T: sa[rb][nc], rows = s (l4*4+r), cols = m (nc*16+l16) ----
    f32x4 sa[2][2];
#pragma unroll
    for (int rb = 0; rb < 2; ++rb)
#pragma unroll
      for (int nc = 0; nc < 2; ++nc) sa[rb][nc] = (f32x4)(0.f);

    __builtin_amdgcn_s_setprio(1);
#pragma unroll
    for (int nc = 0; nc < 2; ++nc) {
      const int row = nc * 16 + l16;
      const unsigned short* kbase = &k_sm[cur][row * DH_];
#pragma unroll
      for (int kk = 0; kk < 4; ++kk) {
        const int gran = (kk * 4 + l4) ^ (row & 7);
        ushort8 bk = *(const ushort8*)(kbase + gran * 8);
        sa[0][nc] = mfma16(aq[0][kk], bk, sa[0][nc]);
        sa[1][nc] = mfma16(aq[1][kk], bk, sa[1][nc]);
      }
    }
    __builtin_amdgcn_s_setprio(0);

    // ---- p = exp2(s) (Q pre-scaled; no max subtraction), pack+store via cvt_pk ----
#pragma unroll
    for (int rb = 0; rb < 2; ++rb) {
#pragma unroll
      for (int r = 0; r < 4; ++r) {
        const float p0 = exp2f_fast(sa[rb][0][r]);
        const float p1 = exp2f_fast(sa[rb][1][r]);
        lsum[rb][r] += p0 + p1;
        unsigned pu;
        asm("v_cvt_pk_bf16_f32 %0, %1, %2" : "=v"(pu) : "v"(p0), "v"(p1));
        unsigned paddr = (unsigned)(size_t)&p_lds[w][rb * 16 + l4 * 4 + r][l16];
        asm volatile("ds_write_b16 %0, %1\n\t"
                     "ds_write_b16_d16_hi %0, %1 offset:32"
                     :: "v"(paddr), "v"(pu) : "memory");
      }
    }

    // ---- PV: A = P rows (s), B = VT rows (d), k-dim = 32 m ----
    ushort8 pf[2];
#pragma unroll
    for (int rb = 0; rb < 2; ++rb)
      pf[rb] = *(const ushort8*)&p_lds[w][rb * 16 + l16][l4 * 8];
    __builtin_amdgcn_s_setprio(1);
#pragma unroll
    for (int nc = 0; nc < 8; ++nc) {
      const int row = nc * 16 + l16;
      const int gran = l4 ^ (row & 3);
      ushort8 bv = *(const ushort8*)&v_sm[cur][row * 32 + gran * 8];
      o_acc[0][nc] = mfma16(pf[0], bv, o_acc[0][nc]);
      o_acc[1][nc] = mfma16(pf[1], bv, o_acc[1][nc]);
    }
    __builtin_amdgcn_s_setprio(0);

    __syncthreads();
    cur ^= 1;
  }
#undef STAGE

  // ---- epilogue: reduce denominators once, normalize, store ----
#pragma unroll
  for (int rb = 0; rb < 2; ++rb)
#pragma unroll
    for (int r = 0; r < 4; ++r) {
      float s = lsum[rb][r];
      s += __shfl_xor(s, 1, 64);
      s += __shfl_xor(s, 2, 64);
      s += __shfl_xor(s, 4, 64);
      s += __shfl_xor(s, 8, 64);
      const float inv = 1.0f / s;
      const int srow = sw + rb * 16 + l4 * 4 + r;
      unsigned short* orow = Ob + ((size_t)b * S_ + srow) * (H_ * DH_) + h * DH_;
#pragma unroll
      for (int nc = 0; nc < 8; ++nc)
        orow[nc * 16 + l16] = f2bf(o_acc[rb][nc][r] * inv);
    }
}

// ---------------- launcher ----------------

extern "C" void kernel_launch(void* const* d_in, const int* in_sizes, int n_in,
                              void* d_out, int out_size, void* d_ws, size_t ws_size,
                              hipStream_t stream) {
  const float* X   = (const float*)d_in[0];
  const float* Wq  = (const float*)d_in[1];
  const float* bq  = (const float*)d_in[2];
  const float* Kp  = (const float*)d_in[3];
  const float* Cal = (const float*)d_in[4];
  const float* V   = (const float*)d_in[5];
  const float* Wd  = (const float*)d_in[6];
  const float* bd  = (const float*)d_in[7];

  char* ws = (char*)d_ws;
  unsigned short* Xbf = (unsigned short*)(ws + 0);          // 67108864 B (reused as Ob)
  unsigned short* Ob  = Xbf;                                 // alias: X dead after GEMM1
  unsigned short* Qb  = (unsigned short*)(ws + 67108864);   // 67108864 B
  unsigned short* WqT = (unsigned short*)(ws + 134217728);  // 8388608 B
  unsigned short* WdT = (unsigned short*)(ws + 142606336);  // 8388608 B
  unsigned short* Kb  = (unsigned short*)(ws + 150994944);  // 4194304 B
  unsigned short* VT  = (unsigned short*)(ws + 155189248);  // 4194304 B

  // conversions
  cvt_bf16<<<2048, 256, 0, stream>>>(X, Xbf, (B_ * S_ * E_) / 4);
  addcvt_bf16<<<1024, 256, 0, stream>>>(Kp, Cal, Kb, (H_ * M_ * DH_) / 4);
  transpose_cvt<<<dim3(E_ / 64, E_ / 64, 1), 256, 0, stream>>>(Wq, WqT, E_, H_ * DH_);
  transpose_cvt<<<dim3(E_ / 64, E_ / 64, 1), 256, 0, stream>>>(Wd, WdT, H_ * DH_, E_);
  transpose_cvt<<<dim3(DH_ / 64, M_ / 64, H_), 256, 0, stream>>>(V, VT, M_, DH_);

  // Q projection: (B*S, E) x (E, H*Dh) -> Q bf16 (B,H,S,Dh), pre-scaled
  gemm256<0><<<dim3(1024), 512, 0, stream>>>(Xbf, WqT, bq, Qb);

  // fused attention -> Ob bf16 (B,S,H*Dh)
  attn_kernel<<<dim3(B_ * H_, S_ / 128), 256, 0, stream>>>(Qb, Kb, VT, Ob);

  // dehead: (B*S, H*Dh) x (H*Dh, E) -> f32 out
  gemm256<1><<<dim3(1024), 512, 0, stream>>>(Ob, WdT, bd, (float*)d_out);
}

// Round 5
// 510.553 us; speedup vs baseline: 2.3309x; 1.1508x over previous
//
#include <hip/hip_runtime.h>
#include <stdint.h>

#define B_ 8
#define S_ 2048
#define E_ 2048
#define H_ 16
#define DH_ 128
#define M_ 1024
#define K_ 2048

typedef float f32x4 __attribute__((ext_vector_type(4)));
typedef __bf16 bf16x8 __attribute__((ext_vector_type(8)));
typedef unsigned short ushort8 __attribute__((ext_vector_type(8)));
typedef unsigned short ushort4v __attribute__((ext_vector_type(4)));
typedef float float4v __attribute__((ext_vector_type(4)));

static __device__ __forceinline__ unsigned short f2bf(float f) {
  unsigned int u = __builtin_bit_cast(unsigned int, f);
  u += 0x7fffu + ((u >> 16) & 1u);
  return (unsigned short)(u >> 16);
}

static __device__ __forceinline__ float exp2f_fast(float x) {
#if __has_builtin(__builtin_amdgcn_exp2f)
  return __builtin_amdgcn_exp2f(x);
#else
  return __expf(x * 0.6931471805599453f);
#endif
}

static __device__ __forceinline__ f32x4 mfma16(ushort8 a, ushort8 b, f32x4 c) {
  return __builtin_amdgcn_mfma_f32_16x16x32_bf16(
      __builtin_bit_cast(bf16x8, a), __builtin_bit_cast(bf16x8, b), c, 0, 0, 0);
}

static __device__ __forceinline__ void gload_lds16(const void* g, void* l) {
  __builtin_amdgcn_global_load_lds(
      (const __attribute__((address_space(1))) unsigned int*)g,
      (__attribute__((address_space(3))) unsigned int*)l, 16, 0, 0);
}

// ---------------- conversion kernels ----------------

__global__ void cvt_bf16(const float* __restrict__ in, unsigned short* __restrict__ out, int n4) {
  int i = blockIdx.x * blockDim.x + threadIdx.x;
  int stride = gridDim.x * blockDim.x;
  for (; i < n4; i += stride) {
    float4v v = ((const float4v*)in)[i];
    ushort4v o;
    o[0] = f2bf(v[0]); o[1] = f2bf(v[1]); o[2] = f2bf(v[2]); o[3] = f2bf(v[3]);
    ((ushort4v*)out)[i] = o;
  }
}

__global__ void addcvt_bf16(const float* __restrict__ a, const float* __restrict__ b,
                            unsigned short* __restrict__ out, int n4) {
  int i = blockIdx.x * blockDim.x + threadIdx.x;
  int stride = gridDim.x * blockDim.x;
  for (; i < n4; i += stride) {
    float4v va = ((const float4v*)a)[i];
    float4v vb = ((const float4v*)b)[i];
    ushort4v o;
    o[0] = f2bf(va[0] + vb[0]); o[1] = f2bf(va[1] + vb[1]);
    o[2] = f2bf(va[2] + vb[2]); o[3] = f2bf(va[3] + vb[3]);
    ((ushort4v*)out)[i] = o;
  }
}

// batched transpose + f32->bf16: in[z][R][C] -> out[z][C][R]
__global__ __launch_bounds__(256) void transpose_cvt(const float* __restrict__ in,
                                                     unsigned short* __restrict__ out,
                                                     int R, int C) {
  __shared__ float t[64][65];
  const int tx = threadIdx.x & 63, ty = threadIdx.x >> 6;  // ty in 0..3
  const size_t base = (size_t)blockIdx.z * R * C;
  const int r0 = blockIdx.y * 64, c0 = blockIdx.x * 64;
#pragma unroll
  for (int i = 0; i < 64; i += 4)
    t[i + ty][tx] = in[base + (size_t)(r0 + i + ty) * C + (c0 + tx)];
  __syncthreads();
#pragma unroll
  for (int i = 0; i < 64; i += 4)
    out[base + (size_t)(c0 + i + ty) * R + (r0 + tx)] = f2bf(t[tx][i + ty]);
}

// ---------------- 8-phase pipelined GEMM ----------------
// C(16384 x 2048) = A(16384 x 2048) * BT(2048 x 2048)^T + bias.
// BM=BN=256, BK=64; 8 waves (2M x 4N); per-wave out 128x64.
// LDS: 2 tensors x 2 buf x 2 k-halves x 16KB = 128 KB, row-pair granule-XOR layout.
// Per K-tile: 4 phases {ds_read || stage-half -> barrier -> lgkmcnt(0) -> 16 MFMA -> barrier};
// vmcnt(6) only at phases 4 & 8 (counted, never 0 mid-loop).
// EPI 0: bf16 Q*(log2e/sqrt(E)) scattered to (B,H,S,Dh); EPI 1: f32 row-major.
template <int EPI>
__global__ __launch_bounds__(512, 2) void gemm8p(const unsigned short* __restrict__ A,
                                                 const unsigned short* __restrict__ BT,
                                                 const float* __restrict__ bias,
                                                 void* __restrict__ Cout) {
  // [buf][kh][slot*8 shorts], slot = rowpair*8 + gg, gg = ((row&1)*4 + g) ^ (rowpair&7)
  __shared__ __align__(16) unsigned short a_lds[2][2][8192];
  __shared__ __align__(16) unsigned short b_lds[2][2][8192];
  const int tid = threadIdx.x;
  const int w = tid >> 6, lane = tid & 63;
  const int l16 = lane & 15, l4 = lane >> 4;
  const int wr = w >> 2, wc = w & 3;  // 2 x 4 wave grid
  const int bid = blockIdx.x;
  const int n0 = (bid & 7) << 8;   // XCD-pinned 1MB B slab
  const int m0 = (bid >> 3) << 8;

  // stage source mapping: LDS slot G=tid holds global (row srow, 16B-granule sg) of the half
  const int rp0 = tid >> 3, gg0 = tid & 7, s0 = gg0 ^ (rp0 & 7);
  const int srow = rp0 * 2 + (s0 >> 2), sg = s0 & 3;
  const unsigned short* pA = A + (size_t)(m0 + srow) * K_ + sg * 8;
  const unsigned short* pB = BT + (size_t)(n0 + srow) * K_ + sg * 8;
  // lane read offset within a 16-row fragment region (shorts)
  const int laneG = ((l16 >> 1) * 8 + (((l16 & 1) * 4 + l4) ^ ((l16 >> 1) & 7))) * 8;

  f32x4 acc[8][4];
#pragma unroll
  for (int i = 0; i < 8; ++i)
#pragma unroll
    for (int j = 0; j < 4; ++j) acc[i][j] = (f32x4)(0.f);

  ushort8 aF[4], bF[4];

#define STG(dst, srcp, T, kh)                                                \
  do {                                                                       \
    const unsigned short* s_ = (srcp) + (T) * 64 + (kh) * 32;                \
    gload_lds16(s_, &(dst)[tid * 8]);                                        \
    gload_lds16(s_ + (size_t)128 * K_, &(dst)[(512 + tid) * 8]);             \
  } while (0)

#define LDA(mg, buf, ks)                                                     \
  do {                                                                       \
    _Pragma("unroll") for (int mf = 0; mf < 4; ++mf)                         \
      aF[mf] = *(const ushort8*)&a_lds[buf][ks]                              \
          [(wr * 512 + ((mg) * 4 + mf) * 64) * 8 + laneG];                   \
  } while (0)

#define LDB(buf, ks)                                                         \
  do {                                                                       \
    _Pragma("unroll") for (int nf = 0; nf < 4; ++nf)                         \
      bF[nf] = *(const ushort8*)&b_lds[buf][ks]                              \
          [(wc * 256 + nf * 64) * 8 + laneG];                                \
  } while (0)

#define MM(mg)                                                               \
  do {                                                                       \
    __builtin_amdgcn_s_setprio(1);                                           \
    _Pragma("unroll") for (int mf = 0; mf < 4; ++mf)                         \
      _Pragma("unroll") for (int nf = 0; nf < 4; ++nf)                       \
        acc[(mg) * 4 + mf][nf] = mfma16(aF[mf], bF[nf], acc[(mg) * 4 + mf][nf]); \
    __builtin_amdgcn_s_setprio(0);                                           \
  } while (0)

#define NOVM ((void)0)
#define VMC6 asm volatile("s_waitcnt vmcnt(6)" ::: "memory")
#define VMC0 asm volatile("s_waitcnt vmcnt(0)" ::: "memory")

#define PHASE(mg, ks, buf, LOADB, STAGE, VM)                                 \
  do {                                                                       \
    if (LOADB) { LDB(buf, ks); }                                             \
    LDA(mg, buf, ks);                                                        \
    STAGE;                                                                   \
    __builtin_amdgcn_s_barrier();                                            \
    asm volatile("s_waitcnt lgkmcnt(0)" ::: "memory");                       \
    __builtin_amdgcn_sched_barrier(0);                                       \
    MM(mg);                                                                  \
    VM;                                                                      \
    __builtin_amdgcn_s_barrier();                                            \
  } while (0)

  // prologue: T0 all 4 halves, then T1.Bk0, T1.Ak0, T1.Bk1 (oldest->newest)
  STG(a_lds[0][0], pA, 0, 0);
  STG(b_lds[0][0], pB, 0, 0);
  STG(a_lds[0][1], pA, 0, 1);
  STG(b_lds[0][1], pB, 0, 1);
  STG(b_lds[1][0], pB, 1, 0);
  STG(a_lds[1][0], pA, 1, 0);
  STG(b_lds[1][1], pB, 1, 1);
  __builtin_amdgcn_sched_barrier(0);
  VMC6;  // T0's 8 loads drained; T1's 3 halves (6 loads) in flight
  __builtin_amdgcn_s_barrier();
  __builtin_amdgcn_sched_barrier(0);

#pragma unroll 1
  for (int i = 0; i < 15; ++i) {
    const int t1 = 2 * i + 1, t2 = 2 * i + 2, t3 = 2 * i + 3;
    PHASE(0, 0, 0, 1, STG(a_lds[1][1], pA, t1, 1), NOVM);
    PHASE(1, 0, 0, 0, STG(b_lds[0][0], pB, t2, 0), NOVM);
    PHASE(1, 1, 0, 1, STG(a_lds[0][0], pA, t2, 0), NOVM);
    PHASE(0, 1, 0, 0, STG(b_lds[0][1], pB, t2, 1), VMC6);
    PHASE(0, 0, 1, 1, STG(a_lds[0][1], pA, t2, 1), NOVM);
    PHASE(1, 0, 1, 0, STG(b_lds[1][0], pB, t3, 0), NOVM);
    PHASE(1, 1, 1, 1, STG(a_lds[1][0], pA, t3, 0), NOVM);
    PHASE(0, 1, 1, 0, STG(b_lds[1][1], pB, t3, 1), VMC6);
  }
  // last iteration (tiles 30, 31): only T31.Ak1 still needs staging
  PHASE(0, 0, 0, 1, STG(a_lds[1][1], pA, 31, 1), NOVM);
  PHASE(1, 0, 0, 0, NOVM, NOVM);
  PHASE(1, 1, 0, 1, NOVM, NOVM);
  PHASE(0, 1, 0, 0, NOVM, VMC0);
  PHASE(0, 0, 1, 1, NOVM, NOVM);
  PHASE(1, 0, 1, 0, NOVM, NOVM);
  PHASE(1, 1, 1, 1, NOVM, NOVM);
  PHASE(0, 1, 1, 0, NOVM, NOVM);

#undef PHASE
#undef STG
#undef LDA
#undef LDB
#undef MM

  // epilogue
#pragma unroll
  for (int mf = 0; mf < 8; ++mf) {
    const int mb = m0 + wr * 128 + mf * 16 + l4 * 4;
#pragma unroll
    for (int nf = 0; nf < 4; ++nf) {
      const int n = n0 + wc * 64 + nf * 16 + l16;
      const float bv = bias[n];
#pragma unroll
      for (int r = 0; r < 4; ++r) {
        const float v = acc[mf][nf][r] + bv;
        const int m = mb + r;
        if (EPI == 0) {
          const int b = m >> 11, s = m & 2047, h = n >> 7, d = n & 127;
          // pre-scale Q by log2(e)/sqrt(E) so attn uses exp2 directly
          ((unsigned short*)Cout)[(((size_t)(b * 16 + h) << 11) + s) * 128 + d] =
              f2bf(v * 0.031879358f);
        } else {
          ((float*)Cout)[(size_t)m * E_ + n] = v;
        }
      }
    }
  }
}

// ---------------- fused attention (no-max softmax, LDS-staged K/V) ----------------
// grid: (B*H, S/128); block 256 (4 waves x 32 rows). wgid%8 == bh%8 -> per-head XCD affinity.
__global__ __launch_bounds__(256) void attn_kernel(const unsigned short* __restrict__ Qb,
                                                   const unsigned short* __restrict__ Kb,
                                                   const unsigned short* __restrict__ VT,
                                                   unsigned short* __restrict__ Ob) {
  const int bh = blockIdx.x, b = bh >> 4, h = bh & 15;
  const int s0 = blockIdx.y << 7;
  const int tid = threadIdx.x, w = tid >> 6, lane = tid & 63;
  const int l16 = lane & 15, l4 = lane >> 4;
  const int sw = s0 + w * 32;

  __shared__ __align__(16) unsigned short k_sm[2][32 * 128];
  __shared__ __align__(16) unsigned short v_sm[2][128 * 32];
  __shared__ __align__(16) unsigned short p_lds[4][32][40];  // 80B row stride

  const unsigned short* Kh = Kb + (size_t)h * M_ * DH_;
  const unsigned short* Vh = VT + (size_t)h * DH_ * M_;

  // Q fragments (pre-scaled by log2e/sqrt(E) in GEMM1 epilogue)
  ushort8 aq[2][4];
  {
    const unsigned short* Qbase = Qb + ((size_t)(b * 16 + h) * S_ + sw) * DH_;
#pragma unroll
    for (int rb = 0; rb < 2; ++rb) {
      const unsigned short* qrow = Qbase + (size_t)(rb * 16 + l16) * DH_ + l4 * 8;
#pragma unroll
      for (int kk = 0; kk < 4; ++kk) aq[rb][kk] = *(const ushort8*)(qrow + kk * 32);
    }
  }

  float lsum[2][4];
  f32x4 o_acc[2][8];
#pragma unroll
  for (int rb = 0; rb < 2; ++rb) {
#pragma unroll
    for (int r = 0; r < 4; ++r) lsum[rb][r] = 0.f;
#pragma unroll
    for (int nc = 0; nc < 8; ++nc) o_acc[rb][nc] = (f32x4)(0.f);
  }

#define STAGE(bufidx, mc_)                                                              \
  do {                                                                                  \
    const int m0s = (mc_) << 5;                                                         \
    unsigned short* kdst = &k_sm[bufidx][0];                                            \
    unsigned short* vdst = &v_sm[bufidx][0];                                            \
    _Pragma("unroll") for (int i_ = 0; i_ < 2; ++i_) {                                  \
      const int g_ = i_ * 256 + tid;                                                    \
      const int kr = g_ >> 4, kc = g_ & 15;                                             \
      gload_lds16(Kh + (size_t)(m0s + kr) * DH_ + ((kc ^ (kr & 7)) << 3), kdst + g_ * 8); \
      const int vd = g_ >> 2, vc = g_ & 3;                                              \
      gload_lds16(Vh + (size_t)vd * M_ + m0s + ((vc ^ (vd & 3)) << 3), vdst + g_ * 8);  \
    }                                                                                   \
  } while (0)

  int cur = 0;
  STAGE(0, 0);
  __syncthreads();

  for (int mc = 0; mc < 32; ++mc) {
    if (mc < 31) STAGE(cur ^ 1, mc + 1);

    // ---- QK^T: sa[rb][nc], rows = s (l4*4+r), cols = m (nc*16+l16) ----
    f32x4 sa[2][2];
#pragma unroll
    for (int rb = 0; rb < 2; ++rb)
#pragma unroll
      for (int nc = 0; nc < 2; ++nc) sa[rb][nc] = (f32x4)(0.f);

    __builtin_amdgcn_s_setprio(1);
#pragma unroll
    for (int nc = 0; nc < 2; ++nc) {
      const int row = nc * 16 + l16;
      const unsigned short* kbase = &k_sm[cur][row * DH_];
#pragma unroll
      for (int kk = 0; kk < 4; ++kk) {
        const int gran = (kk * 4 + l4) ^ (row & 7);
        ushort8 bk = *(const ushort8*)(kbase + gran * 8);
        sa[0][nc] = mfma16(aq[0][kk], bk, sa[0][nc]);
        sa[1][nc] = mfma16(aq[1][kk], bk, sa[1][nc]);
      }
    }
    __builtin_amdgcn_s_setprio(0);

    // ---- p = exp2(s) (Q pre-scaled; no max subtraction), pack+store via cvt_pk ----
#pragma unroll
    for (int rb = 0; rb < 2; ++rb) {
#pragma unroll
      for (int r = 0; r < 4; ++r) {
        const float p0 = exp2f_fast(sa[rb][0][r]);
        const float p1 = exp2f_fast(sa[rb][1][r]);
        lsum[rb][r] += p0 + p1;
        unsigned pu;
        asm("v_cvt_pk_bf16_f32 %0, %1, %2" : "=v"(pu) : "v"(p0), "v"(p1));
        unsigned paddr = (unsigned)(size_t)&p_lds[w][rb * 16 + l4 * 4 + r][l16];
        asm volatile("ds_write_b16 %0, %1\n\t"
                     "ds_write_b16_d16_hi %0, %1 offset:32"
                     :: "v"(paddr), "v"(pu) : "memory");
      }
    }

    // ---- PV: A = P rows (s), B = VT rows (d), k-dim = 32 m ----
    ushort8 pf[2];
#pragma unroll
    for (int rb = 0; rb < 2; ++rb)
      pf[rb] = *(const ushort8*)&p_lds[w][rb * 16 + l16][l4 * 8];
    __builtin_amdgcn_s_setprio(1);
#pragma unroll
    for (int nc = 0; nc < 8; ++nc) {
      const int row = nc * 16 + l16;
      const int gran = l4 ^ (row & 3);
      ushort8 bv = *(const ushort8*)&v_sm[cur][row * 32 + gran * 8];
      o_acc[0][nc] = mfma16(pf[0], bv, o_acc[0][nc]);
      o_acc[1][nc] = mfma16(pf[1], bv, o_acc[1][nc]);
    }
    __builtin_amdgcn_s_setprio(0);

    __syncthreads();
    cur ^= 1;
  }
#undef STAGE

  // ---- epilogue: reduce denominators once, normalize, store ----
#pragma unroll
  for (int rb = 0; rb < 2; ++rb)
#pragma unroll
    for (int r = 0; r < 4; ++r) {
      float s = lsum[rb][r];
      s += __shfl_xor(s, 1, 64);
      s += __shfl_xor(s, 2, 64);
      s += __shfl_xor(s, 4, 64);
      s += __shfl_xor(s, 8, 64);
      const float inv = 1.0f / s;
      const int srow = sw + rb * 16 + l4 * 4 + r;
      unsigned short* orow = Ob + ((size_t)b * S_ + srow) * (H_ * DH_) + h * DH_;
#pragma unroll
      for (int nc = 0; nc < 8; ++nc)
        orow[nc * 16 + l16] = f2bf(o_acc[rb][nc][r] * inv);
    }
}

// ---------------- launcher ----------------

extern "C" void kernel_launch(void* const* d_in, const int* in_sizes, int n_in,
                              void* d_out, int out_size, void* d_ws, size_t ws_size,
                              hipStream_t stream) {
  const float* X   = (const float*)d_in[0];
  const float* Wq  = (const float*)d_in[1];
  const float* bq  = (const float*)d_in[2];
  const float* Kp  = (const float*)d_in[3];
  const float* Cal = (const float*)d_in[4];
  const float* V   = (const float*)d_in[5];
  const float* Wd  = (const float*)d_in[6];
  const float* bd  = (const float*)d_in[7];

  char* ws = (char*)d_ws;
  unsigned short* Xbf = (unsigned short*)(ws + 0);          // 67108864 B (reused as Ob)
  unsigned short* Ob  = Xbf;                                 // alias: X dead after GEMM1
  unsigned short* Qb  = (unsigned short*)(ws + 67108864);   // 67108864 B
  unsigned short* WqT = (unsigned short*)(ws + 134217728);  // 8388608 B
  unsigned short* WdT = (unsigned short*)(ws + 142606336);  // 8388608 B
  unsigned short* Kb  = (unsigned short*)(ws + 150994944);  // 4194304 B
  unsigned short* VT  = (unsigned short*)(ws + 155189248);  // 4194304 B

  // conversions
  cvt_bf16<<<2048, 256, 0, stream>>>(X, Xbf, (B_ * S_ * E_) / 4);
  addcvt_bf16<<<1024, 256, 0, stream>>>(Kp, Cal, Kb, (H_ * M_ * DH_) / 4);
  transpose_cvt<<<dim3(E_ / 64, E_ / 64, 1), 256, 0, stream>>>(Wq, WqT, E_, H_ * DH_);
  transpose_cvt<<<dim3(E_ / 64, E_ / 64, 1), 256, 0, stream>>>(Wd, WdT, H_ * DH_, E_);
  transpose_cvt<<<dim3(DH_ / 64, M_ / 64, H_), 256, 0, stream>>>(V, VT, M_, DH_);

  // Q projection: (B*S, E) x (E, H*Dh) -> Q bf16 (B,H,S,Dh), pre-scaled
  gemm8p<0><<<dim3(512), 512, 0, stream>>>(Xbf, WqT, bq, Qb);

  // fused attention -> Ob bf16 (B,S,H*Dh)
  attn_kernel<<<dim3(B_ * H_, S_ / 128), 256, 0, stream>>>(Qb, Kb, VT, Ob);

  // dehead: (B*S, H*Dh) x (H*Dh, E) -> f32 out
  gemm8p<1><<<dim3(512), 512, 0, stream>>>(Ob, WdT, bd, (float*)d_out);
}

// Round 6
// 474.783 us; speedup vs baseline: 2.5065x; 1.0753x over previous
//
#include <hip/hip_runtime.h>
#include <stdint.h>

#define B_ 8
#define S_ 2048
#define E_ 2048
#define H_ 16
#define DH_ 128
#define M_ 1024
#define K_ 2048

typedef float f32x4 __attribute__((ext_vector_type(4)));
typedef float f32x16 __attribute__((ext_vector_type(16)));
typedef __bf16 bf16x8 __attribute__((ext_vector_type(8)));
typedef unsigned short ushort8 __attribute__((ext_vector_type(8)));
typedef unsigned short ushort4v __attribute__((ext_vector_type(4)));
typedef unsigned int uint4v __attribute__((ext_vector_type(4)));
typedef float float4v __attribute__((ext_vector_type(4)));

static __device__ __forceinline__ unsigned short f2bf(float f) {
  unsigned int u = __builtin_bit_cast(unsigned int, f);
  u += 0x7fffu + ((u >> 16) & 1u);
  return (unsigned short)(u >> 16);
}

static __device__ __forceinline__ float exp2f_fast(float x) {
#if __has_builtin(__builtin_amdgcn_exp2f)
  return __builtin_amdgcn_exp2f(x);
#else
  return __expf(x * 0.6931471805599453f);
#endif
}

static __device__ __forceinline__ f32x4 mfma16(ushort8 a, ushort8 b, f32x4 c) {
  return __builtin_amdgcn_mfma_f32_16x16x32_bf16(
      __builtin_bit_cast(bf16x8, a), __builtin_bit_cast(bf16x8, b), c, 0, 0, 0);
}

static __device__ __forceinline__ f32x16 mfma32(ushort8 a, ushort8 b, f32x16 c) {
  return __builtin_amdgcn_mfma_f32_32x32x16_bf16(
      __builtin_bit_cast(bf16x8, a), __builtin_bit_cast(bf16x8, b), c, 0, 0, 0);
}

static __device__ __forceinline__ void gload_lds16(const void* g, void* l) {
  __builtin_amdgcn_global_load_lds(
      (const __attribute__((address_space(1))) unsigned int*)g,
      (__attribute__((address_space(3))) unsigned int*)l, 16, 0, 0);
}

// ---------------- conversion kernels ----------------

__global__ void cvt_bf16(const float* __restrict__ in, unsigned short* __restrict__ out, int n4) {
  int i = blockIdx.x * blockDim.x + threadIdx.x;
  int stride = gridDim.x * blockDim.x;
  for (; i < n4; i += stride) {
    float4v v = ((const float4v*)in)[i];
    ushort4v o;
    o[0] = f2bf(v[0]); o[1] = f2bf(v[1]); o[2] = f2bf(v[2]); o[3] = f2bf(v[3]);
    ((ushort4v*)out)[i] = o;
  }
}

__global__ void addcvt_bf16(const float* __restrict__ a, const float* __restrict__ b,
                            unsigned short* __restrict__ out, int n4) {
  int i = blockIdx.x * blockDim.x + threadIdx.x;
  int stride = gridDim.x * blockDim.x;
  for (; i < n4; i += stride) {
    float4v va = ((const float4v*)a)[i];
    float4v vb = ((const float4v*)b)[i];
    ushort4v o;
    o[0] = f2bf(va[0] + vb[0]); o[1] = f2bf(va[1] + vb[1]);
    o[2] = f2bf(va[2] + vb[2]); o[3] = f2bf(va[3] + vb[3]);
    ((ushort4v*)out)[i] = o;
  }
}

// batched transpose + f32->bf16: in[z][R][C] -> out[z][C][R]
__global__ __launch_bounds__(256) void transpose_cvt(const float* __restrict__ in,
                                                     unsigned short* __restrict__ out,
                                                     int R, int C) {
  __shared__ float t[64][65];
  const int tx = threadIdx.x & 63, ty = threadIdx.x >> 6;  // ty in 0..3
  const size_t base = (size_t)blockIdx.z * R * C;
  const int r0 = blockIdx.y * 64, c0 = blockIdx.x * 64;
#pragma unroll
  for (int i = 0; i < 64; i += 4)
    t[i + ty][tx] = in[base + (size_t)(r0 + i + ty) * C + (c0 + tx)];
  __syncthreads();
#pragma unroll
  for (int i = 0; i < 64; i += 4)
    out[base + (size_t)(c0 + i + ty) * R + (r0 + tx)] = f2bf(t[tx][i + ty]);
}

// ---------------- 8-phase pipelined GEMM ----------------
// C(16384 x 2048) = A(16384 x 2048) * BT(2048 x 2048)^T + bias.
// BM=BN=256, BK=64; 8 waves (2M x 4N); per-wave out 128x64.
template <int EPI>
__global__ __launch_bounds__(512, 2) void gemm8p(const unsigned short* __restrict__ A,
                                                 const unsigned short* __restrict__ BT,
                                                 const float* __restrict__ bias,
                                                 void* __restrict__ Cout) {
  __shared__ __align__(16) unsigned short a_lds[2][2][8192];
  __shared__ __align__(16) unsigned short b_lds[2][2][8192];
  const int tid = threadIdx.x;
  const int w = tid >> 6, lane = tid & 63;
  const int l16 = lane & 15, l4 = lane >> 4;
  const int wr = w >> 2, wc = w & 3;  // 2 x 4 wave grid
  const int bid = blockIdx.x;
  const int n0 = (bid & 7) << 8;   // XCD-pinned 1MB B slab
  const int m0 = (bid >> 3) << 8;

  const int rp0 = tid >> 3, gg0 = tid & 7, s0 = gg0 ^ (rp0 & 7);
  const int srow = rp0 * 2 + (s0 >> 2), sg = s0 & 3;
  const unsigned short* pA = A + (size_t)(m0 + srow) * K_ + sg * 8;
  const unsigned short* pB = BT + (size_t)(n0 + srow) * K_ + sg * 8;
  const int laneG = ((l16 >> 1) * 8 + (((l16 & 1) * 4 + l4) ^ ((l16 >> 1) & 7))) * 8;

  f32x4 acc[8][4];
#pragma unroll
  for (int i = 0; i < 8; ++i)
#pragma unroll
    for (int j = 0; j < 4; ++j) acc[i][j] = (f32x4)(0.f);

  ushort8 aF[4], bF[4];

#define STG(dst, srcp, T, kh)                                                \
  do {                                                                       \
    const unsigned short* s_ = (srcp) + (T) * 64 + (kh) * 32;                \
    gload_lds16(s_, &(dst)[tid * 8]);                                        \
    gload_lds16(s_ + (size_t)128 * K_, &(dst)[(512 + tid) * 8]);             \
  } while (0)

#define LDA(mg, buf, ks)                                                     \
  do {                                                                       \
    _Pragma("unroll") for (int mf = 0; mf < 4; ++mf)                         \
      aF[mf] = *(const ushort8*)&a_lds[buf][ks]                              \
          [(wr * 512 + ((mg) * 4 + mf) * 64) * 8 + laneG];                   \
  } while (0)

#define LDB(buf, ks)                                                         \
  do {                                                                       \
    _Pragma("unroll") for (int nf = 0; nf < 4; ++nf)                         \
      bF[nf] = *(const ushort8*)&b_lds[buf][ks]                              \
          [(wc * 256 + nf * 64) * 8 + laneG];                                \
  } while (0)

#define MM(mg)                                                               \
  do {                                                                       \
    __builtin_amdgcn_s_setprio(1);                                           \
    _Pragma("unroll") for (int mf = 0; mf < 4; ++mf)                         \
      _Pragma("unroll") for (int nf = 0; nf < 4; ++nf)                       \
        acc[(mg) * 4 + mf][nf] = mfma16(aF[mf], bF[nf], acc[(mg) * 4 + mf][nf]); \
    __builtin_amdgcn_s_setprio(0);                                           \
  } while (0)

#define NOVM ((void)0)
#define VMC6 asm volatile("s_waitcnt vmcnt(6)" ::: "memory")
#define VMC0 asm volatile("s_waitcnt vmcnt(0)" ::: "memory")

#define PHASE(mg, ks, buf, LOADB, STAGE, VM)                                 \
  do {                                                                       \
    if (LOADB) { LDB(buf, ks); }                                             \
    LDA(mg, buf, ks);                                                        \
    STAGE;                                                                   \
    __builtin_amdgcn_s_barrier();                                            \
    asm volatile("s_waitcnt lgkmcnt(0)" ::: "memory");                       \
    __builtin_amdgcn_sched_barrier(0);                                       \
    MM(mg);                                                                  \
    VM;                                                                      \
    __builtin_amdgcn_s_barrier();                                            \
  } while (0)

  STG(a_lds[0][0], pA, 0, 0);
  STG(b_lds[0][0], pB, 0, 0);
  STG(a_lds[0][1], pA, 0, 1);
  STG(b_lds[0][1], pB, 0, 1);
  STG(b_lds[1][0], pB, 1, 0);
  STG(a_lds[1][0], pA, 1, 0);
  STG(b_lds[1][1], pB, 1, 1);
  __builtin_amdgcn_sched_barrier(0);
  VMC6;
  __builtin_amdgcn_s_barrier();
  __builtin_amdgcn_sched_barrier(0);

#pragma unroll 1
  for (int i = 0; i < 15; ++i) {
    const int t1 = 2 * i + 1, t2 = 2 * i + 2, t3 = 2 * i + 3;
    PHASE(0, 0, 0, 1, STG(a_lds[1][1], pA, t1, 1), NOVM);
    PHASE(1, 0, 0, 0, STG(b_lds[0][0], pB, t2, 0), NOVM);
    PHASE(1, 1, 0, 1, STG(a_lds[0][0], pA, t2, 0), NOVM);
    PHASE(0, 1, 0, 0, STG(b_lds[0][1], pB, t2, 1), VMC6);
    PHASE(0, 0, 1, 1, STG(a_lds[0][1], pA, t2, 1), NOVM);
    PHASE(1, 0, 1, 0, STG(b_lds[1][0], pB, t3, 0), NOVM);
    PHASE(1, 1, 1, 1, STG(a_lds[1][0], pA, t3, 0), NOVM);
    PHASE(0, 1, 1, 0, STG(b_lds[1][1], pB, t3, 1), VMC6);
  }
  PHASE(0, 0, 0, 1, STG(a_lds[1][1], pA, 31, 1), NOVM);
  PHASE(1, 0, 0, 0, NOVM, NOVM);
  PHASE(1, 1, 0, 1, NOVM, NOVM);
  PHASE(0, 1, 0, 0, NOVM, VMC0);
  PHASE(0, 0, 1, 1, NOVM, NOVM);
  PHASE(1, 0, 1, 0, NOVM, NOVM);
  PHASE(1, 1, 1, 1, NOVM, NOVM);
  PHASE(0, 1, 1, 0, NOVM, NOVM);

#undef PHASE
#undef STG
#undef LDA
#undef LDB
#undef MM

#pragma unroll
  for (int mf = 0; mf < 8; ++mf) {
    const int mb = m0 + wr * 128 + mf * 16 + l4 * 4;
#pragma unroll
    for (int nf = 0; nf < 4; ++nf) {
      const int n = n0 + wc * 64 + nf * 16 + l16;
      const float bv = bias[n];
#pragma unroll
      for (int r = 0; r < 4; ++r) {
        const float v = acc[mf][nf][r] + bv;
        const int m = mb + r;
        if (EPI == 0) {
          const int b = m >> 11, s = m & 2047, h = n >> 7, d = n & 127;
          // pre-scale Q by log2(e)/sqrt(E) so attn uses exp2 directly
          ((unsigned short*)Cout)[(((size_t)(b * 16 + h) << 11) + s) * 128 + d] =
              f2bf(v * 0.031879358f);
        } else {
          ((float*)Cout)[(size_t)m * E_ + n] = v;
        }
      }
    }
  }
}

// ---------------- fused attention: 8-wave, 32x32 swapped-QK^T, in-register softmax --
// grid: (B*H, S/256); block 512 (8 waves x 32 q-rows). wgid%8 == bh%8 -> XCD affinity.
// QK^T: D = mfma32(K, Q): col = lane&31 = q-row s; regs = m: crow(r,hi)=(r&3)+8(r>>2)+4hi.
// Softmax: no max subtraction (scores |s|<~2 after log2e/sqrt(E) pre-scale); per-lane
// exp2 + scalar lsum. P -> bf16 PV A-frags via cvt_pk + permlane32_swap (T12).
__global__ __launch_bounds__(512, 2) void attn32(const unsigned short* __restrict__ Qb,
                                                 const unsigned short* __restrict__ Kb,
                                                 const unsigned short* __restrict__ VT,
                                                 unsigned short* __restrict__ Ob) {
  const int bh = blockIdx.x, b = bh >> 4, h = bh & 15;
  const int tid = threadIdx.x, wv = tid >> 6, lane = tid & 63;
  const int l32 = lane & 31, hi = lane >> 5;
  const int s_glob = blockIdx.y * 256 + wv * 32 + l32;

  // K: [64 m][128 d], 16B granules XOR'd by (m&7) -> 8-lane read groups hit 32 banks exactly.
  // V: [128 d][64 m], granules XOR'd by (d&7).
  __shared__ __align__(16) unsigned short k_sm[2][64 * 128];
  __shared__ __align__(16) unsigned short v_sm[2][128 * 64];
  __shared__ float inv_lds[8][32];

  const unsigned short* Kh = Kb + (size_t)h * M_ * DH_;
  const unsigned short* Vh = VT + (size_t)h * DH_ * M_;

  // Q fragments (B-operand: col=s, k = d = dc*16 + hi*8 + j); pre-scaled in GEMM1.
  ushort8 qf[8];
  {
    const unsigned short* qrow = Qb + ((size_t)(b * 16 + h) * S_ + s_glob) * DH_ + hi * 8;
#pragma unroll
    for (int dc = 0; dc < 8; ++dc) qf[dc] = *(const ushort8*)(qrow + dc * 16);
  }

  f32x16 oacc[4];
#pragma unroll
  for (int dt = 0; dt < 4; ++dt) oacc[dt] = (f32x16)(0.f);
  float lsum = 0.f;

#define ASTAGE(buf, ch)                                                        \
  do {                                                                         \
    const int m0_ = (ch) << 6;                                                 \
    _Pragma("unroll") for (int j_ = 0; j_ < 2; ++j_) {                         \
      const int t_ = j_ * 512 + tid;                                           \
      const int m_ = t_ >> 4, p_ = t_ & 15;                                    \
      gload_lds16(Kh + (size_t)(m0_ + m_) * DH_ + ((p_ ^ (m_ & 7)) << 3),      \
                  &k_sm[buf][t_ * 8]);                                         \
    }                                                                          \
    _Pragma("unroll") for (int j_ = 0; j_ < 2; ++j_) {                         \
      const int t_ = j_ * 512 + tid;                                           \
      const int d_ = t_ >> 3, p_ = t_ & 7;                                     \
      gload_lds16(Vh + (size_t)d_ * M_ + m0_ + ((p_ ^ (d_ & 7)) << 3),         \
                  &v_sm[buf][t_ * 8]);                                         \
    }                                                                          \
  } while (0)

  int cur = 0;
  ASTAGE(0, 0);
  __syncthreads();

  for (int c = 0; c < 16; ++c) {
    if (c < 15) ASTAGE(cur ^ 1, c + 1);

    // ---- QK^T (swapped): sacc[mb] = K-rows (m) x Q-cols (s) ----
    f32x16 sacc[2];
    sacc[0] = (f32x16)(0.f);
    sacc[1] = (f32x16)(0.f);
#pragma unroll
    for (int mb = 0; mb < 2; ++mb) {
      const int m_ = mb * 32 + l32;
      const unsigned short* kr = &k_sm[cur][m_ * 128];
      __builtin_amdgcn_s_setprio(1);
#pragma unroll
      for (int dc = 0; dc < 8; ++dc) {
        ushort8 kf = *(const ushort8*)(kr + (((dc * 2 + hi) ^ (m_ & 7)) << 3));
        sacc[mb] = mfma32(kf, qf[dc], sacc[mb]);
      }
      __builtin_amdgcn_s_setprio(0);
    }

    // ---- in-register softmax (no max) + pack to PV A-frags + PV ----
#pragma unroll
    for (int mb = 0; mb < 2; ++mb) {
      float pe[16];
#pragma unroll
      for (int r = 0; r < 16; ++r) {
        pe[r] = exp2f_fast(sacc[mb][r]);
        lsum += pe[r];
      }
      ushort8 pa[2];
#pragma unroll
      for (int mk = 0; mk < 2; ++mk) {
        const int o = mk * 8;
        unsigned x0, x1, y0, y1;
        asm("v_cvt_pk_bf16_f32 %0, %1, %2" : "=v"(x0) : "v"(pe[o + 0]), "v"(pe[o + 1]));
        asm("v_cvt_pk_bf16_f32 %0, %1, %2" : "=v"(x1) : "v"(pe[o + 2]), "v"(pe[o + 3]));
        asm("v_cvt_pk_bf16_f32 %0, %1, %2" : "=v"(y0) : "v"(pe[o + 4]), "v"(pe[o + 5]));
        asm("v_cvt_pk_bf16_f32 %0, %1, %2" : "=v"(y1) : "v"(pe[o + 6]), "v"(pe[o + 7]));
        // exchange: dst.hi-lanes <-> src.lo-lanes; assembles k = m-consecutive bf16x8
        asm("v_permlane32_swap_b32 %0, %1" : "+v"(x0), "+v"(y0));
        asm("v_permlane32_swap_b32 %0, %1" : "+v"(x1), "+v"(y1));
        uint4v pw;
        pw[0] = x0; pw[1] = x1; pw[2] = y0; pw[3] = y1;
        pa[mk] = __builtin_bit_cast(ushort8, pw);
      }
#pragma unroll
      for (int dt = 0; dt < 4; ++dt) {
        const int d_ = dt * 32 + l32;
        const unsigned short* vr = &v_sm[cur][d_ * 64];
        __builtin_amdgcn_s_setprio(1);
#pragma unroll
        for (int mk = 0; mk < 2; ++mk) {
          const int gv = mb * 4 + mk * 2 + hi;
          ushort8 vf = *(const ushort8*)(vr + ((gv ^ (d_ & 7)) << 3));
          oacc[dt] = mfma32(pa[mk], vf, oacc[dt]);
        }
        __builtin_amdgcn_s_setprio(0);
      }
    }
    __syncthreads();
    cur ^= 1;
  }
#undef ASTAGE

  // ---- epilogue: denominator (lane + partner half), broadcast inv, store O ----
  float tot = lsum + __shfl_xor(lsum, 32, 64);
  if (hi == 0) inv_lds[wv][l32] = 1.0f / tot;
#pragma unroll
  for (int r = 0; r < 16; ++r) {
    const int srow = (r & 3) + 8 * (r >> 2) + 4 * hi;
    const float iv = inv_lds[wv][srow];
    unsigned short* orow =
        Ob + ((size_t)b * S_ + (size_t)(blockIdx.y * 256 + wv * 32 + srow)) * (H_ * DH_) +
        h * DH_ + l32;
#pragma unroll
    for (int dt = 0; dt < 4; ++dt) {
      const float val = oacc[dt][r] * iv;
      unsigned u;
      asm("v_cvt_pk_bf16_f32 %0, %1, %2" : "=v"(u) : "v"(val), "v"(val));
      orow[dt * 32] = (unsigned short)u;
    }
  }
}

// ---------------- launcher ----------------

extern "C" void kernel_launch(void* const* d_in, const int* in_sizes, int n_in,
                              void* d_out, int out_size, void* d_ws, size_t ws_size,
                              hipStream_t stream) {
  const float* X   = (const float*)d_in[0];
  const float* Wq  = (const float*)d_in[1];
  const float* bq  = (const float*)d_in[2];
  const float* Kp  = (const float*)d_in[3];
  const float* Cal = (const float*)d_in[4];
  const float* V   = (const float*)d_in[5];
  const float* Wd  = (const float*)d_in[6];
  const float* bd  = (const float*)d_in[7];

  char* ws = (char*)d_ws;
  unsigned short* Xbf = (unsigned short*)(ws + 0);          // 67108864 B (reused as Ob)
  unsigned short* Ob  = Xbf;                                 // alias: X dead after GEMM1
  unsigned short* Qb  = (unsigned short*)(ws + 67108864);   // 67108864 B
  unsigned short* WqT = (unsigned short*)(ws + 134217728);  // 8388608 B
  unsigned short* WdT = (unsigned short*)(ws + 142606336);  // 8388608 B
  unsigned short* Kb  = (unsigned short*)(ws + 150994944);  // 4194304 B
  unsigned short* VT  = (unsigned short*)(ws + 155189248);  // 4194304 B

  // conversions
  cvt_bf16<<<2048, 256, 0, stream>>>(X, Xbf, (B_ * S_ * E_) / 4);
  addcvt_bf16<<<1024, 256, 0, stream>>>(Kp, Cal, Kb, (H_ * M_ * DH_) / 4);
  transpose_cvt<<<dim3(E_ / 64, E_ / 64, 1), 256, 0, stream>>>(Wq, WqT, E_, H_ * DH_);
  transpose_cvt<<<dim3(E_ / 64, E_ / 64, 1), 256, 0, stream>>>(Wd, WdT, H_ * DH_, E_);
  transpose_cvt<<<dim3(DH_ / 64, M_ / 64, H_), 256, 0, stream>>>(V, VT, M_, DH_);

  // Q projection: (B*S, E) x (E, H*Dh) -> Q bf16 (B,H,S,Dh), pre-scaled
  gemm8p<0><<<dim3(512), 512, 0, stream>>>(Xbf, WqT, bq, Qb);

  // fused attention -> Ob bf16 (B,S,H*Dh)
  attn32<<<dim3(B_ * H_, S_ / 256), 512, 0, stream>>>(Qb, Kb, VT, Ob);

  // dehead: (B*S, H*Dh) x (H*Dh, E) -> f32 out
  gemm8p<1><<<dim3(512), 512, 0, stream>>>(Ob, WdT, bd, (float*)d_out);
}